// Round 6
// baseline (326.916 us; speedup 1.0000x reference)
//
#include <hip/hip_runtime.h>
#include <cstdint>
#include <cstddef>

#define NEG_SLOPE 0.2f

__device__ __forceinline__ float elu_f(float x) {
    return x > 0.f ? x : expm1f(x);
}

// ---------------------------------------------------------------------------
// P0: zero cnt + ready, detect edge-index layout, compute folded attention
// vectors for all 3 layers. Blocks 0..78 zero; blocks 79..84 fold.
// vfold[l][k*8+j] = sum_cc W_l[k, h*64+cc]*att[h,cc] (j<4 src, j>=4 dst, h=j&3)
// ---------------------------------------------------------------------------
__global__ __launch_bounds__(256) void prep_kernel(
    const int* __restrict__ ei,
    const float* __restrict__ W0, const float* __restrict__ as0, const float* __restrict__ ad0,
    const float* __restrict__ W1, const float* __restrict__ as1, const float* __restrict__ ad1,
    const float* __restrict__ W2, const float* __restrict__ as2, const float* __restrict__ ad2,
    int* __restrict__ cnt, int* __restrict__ ready, int* __restrict__ flag,
    float* __restrict__ vfold, int n) {
    const int b = blockIdx.x, t = threadIdx.x;
    if (b < 79) {
        const int i = b * 256 + t;
        if (i < n) cnt[i] = 0;
        if (b == 0) {
            if (t < 128) ready[t] = 0;
            if (t == 0) {
                int acc = 0;
#pragma unroll
                for (int k = 0; k < 8; ++k) acc |= ei[2 * k + 1];
                flag[0] = (acc == 0) ? 1 : 0;
            }
        }
        return;
    }
    const int e = (b - 79) * 256 + t;
    if (e >= 1536) return;
    const int l = e >> 9, rem = e & 511;
    const int k = rem >> 3, j = rem & 7, h = j & 3;
    const float* W   = (l == 0) ? W0  : (l == 1) ? W1  : W2;
    const float* as_ = (l == 0) ? as0 : (l == 1) ? as1 : as2;
    const float* ad_ = (l == 0) ? ad0 : (l == 1) ? ad1 : ad2;
    const float* av = (j < 4) ? as_ : ad_;
    const float* wr = W + k * 256 + h * 64;
    const float* ar = av + h * 64;
    float s = 0.f;
#pragma unroll 8
    for (int cc = 0; cc < 64; ++cc) s += wr[cc] * ar[cc];
    vfold[l * 512 + k * 8 + j] = s;
}

__global__ void count_kernel(const int* __restrict__ ei, const int* __restrict__ flag,
                             int E, int Etot, int* __restrict__ cnt) {
    int e = blockIdx.x * blockDim.x + threadIdx.x;
    if (e >= Etot) return;
    int d;
    if (e < E) d = flag[0] ? ei[2 * (size_t)(E + e)] : ei[E + e];
    else       d = e - E;  // self loop
    atomicAdd(&cnt[d], 1);
}

// ---------------------------------------------------------------------------
// One-pass scan with parallel lookback (79 co-resident blocks).
// ---------------------------------------------------------------------------
#define SCAN_B 256
__global__ __launch_bounds__(256) void scan_onepass_kernel(
    const int* __restrict__ cnt, int* __restrict__ ready,
    int* __restrict__ rowptr, int* __restrict__ cursor, int n) {
    __shared__ int sd[SCAN_B];
    __shared__ int sred[128];
    __shared__ int s_pref;
    const int b = blockIdx.x, t = threadIdx.x;
    const int g = b * SCAN_B + t;
    const int v = (g < n) ? cnt[g] : 0;
    sd[t] = v;
    __syncthreads();
    for (int off = 1; off < SCAN_B; off <<= 1) {
        int add = (t >= off) ? sd[t - off] : 0;
        __syncthreads();
        sd[t] += add;
        __syncthreads();
    }
    if (t == SCAN_B - 1) atomicExch(&ready[b], sd[SCAN_B - 1] + 1);
    if (t < 128) {
        int pv = 0;
        if (t < b) {
            do { pv = atomicAdd(&ready[t], 0); __builtin_amdgcn_s_sleep(1); } while (pv == 0);
            pv -= 1;
        }
        sred[t] = pv;
    }
    __syncthreads();
    if (t == 0) {
        int s = 0;
#pragma unroll 8
        for (int i = 0; i < 128; ++i) s += sred[i];
        s_pref = s;
    }
    __syncthreads();
    const int pre = s_pref;
    if (g < n) {
        const int e = pre + sd[t];
        rowptr[g + 1] = e;
        cursor[g] = e - v;
        if (g == 0) rowptr[0] = 0;
    }
}

// ---------------------------------------------------------------------------
// fill (CSR scatter) + encoder merged into one dispatch: blocks [0,FB) do the
// CSR fill, blocks [FB, FB+ceil(N/64)) run the encoder.
// ---------------------------------------------------------------------------
#define H1STR 68
__global__ __launch_bounds__(256) void fillenc_kernel(
    const int* __restrict__ ei, const int* __restrict__ flag,
    int E, int Etot, int* __restrict__ cursor, int* __restrict__ col, int FB,
    const float* __restrict__ x,
    const float* __restrict__ W1, const float* __restrict__ b1,
    const float* __restrict__ W2, const float* __restrict__ b2,
    const float* __restrict__ vfold0,
    float* __restrict__ h0, float* __restrict__ asrc, float* __restrict__ adst,
    int n_nodes) {
    if (blockIdx.x < FB) {
        const int e = blockIdx.x * 256 + threadIdx.x;
        if (e >= Etot) return;
        int s, d;
        if (e < E) {
            if (flag[0]) { s = ei[2 * (size_t)e]; d = ei[2 * (size_t)(E + e)]; }
            else         { s = ei[e];             d = ei[E + e]; }
        } else {
            s = d = e - E;
        }
        int pos = atomicAdd(&cursor[d], 1);
        col[pos] = s;
        return;
    }
    __shared__ float W1s[256];
    __shared__ float b1s[32];
    __shared__ float W2s[2048];
    __shared__ float b2s[64];
    __shared__ float vsd[512];
    __shared__ float xS[512];            // 64 nodes x 8
    __shared__ float h1T[32 * H1STR];    // [k][node]
    const int t = threadIdx.x;
    const int n0 = (blockIdx.x - FB) * 64;
    const int rem = n_nodes - n0;

    *(float4*)(W2s + t * 4) = *(const float4*)(W2 + t * 4);
    *(float4*)(W2s + 1024 + t * 4) = *(const float4*)(W2 + 1024 + t * 4);
    if (t < 64)  *(float4*)(W1s + t * 4) = *(const float4*)(W1 + t * 4);
    if (t < 8)   *(float4*)(b1s + t * 4) = *(const float4*)(b1 + t * 4);
    if (t < 16)  *(float4*)(b2s + t * 4) = *(const float4*)(b2 + t * 4);
    if (t < 128) *(float4*)(vsd + t * 4) = *(const float4*)(vfold0 + t * 4);
    if (t < 128) {
        const int fidx = t * 4;
        float4 v = make_float4(0.f, 0.f, 0.f, 0.f);
        if (fidx < rem * 8) v = *(const float4*)(x + (size_t)n0 * 8 + fidx);
        *(float4*)(xS + fidx) = v;
    }
    __syncthreads();

    {
        const int nl = t >> 2;
        const int j0 = (t & 3) * 8;
        const float4 xa = *(const float4*)(xS + nl * 8);
        const float4 xb = *(const float4*)(xS + nl * 8 + 4);
        const float xk[8] = {xa.x, xa.y, xa.z, xa.w, xb.x, xb.y, xb.z, xb.w};
        float a[8];
#pragma unroll
        for (int u = 0; u < 8; ++u) a[u] = b1s[j0 + u];
#pragma unroll
        for (int k = 0; k < 8; ++k) {
            const float4 w0 = *(const float4*)(W1s + k * 32 + j0);
            const float4 w1 = *(const float4*)(W1s + k * 32 + j0 + 4);
            a[0] += xk[k] * w0.x; a[1] += xk[k] * w0.y;
            a[2] += xk[k] * w0.z; a[3] += xk[k] * w0.w;
            a[4] += xk[k] * w1.x; a[5] += xk[k] * w1.y;
            a[6] += xk[k] * w1.z; a[7] += xk[k] * w1.w;
        }
#pragma unroll
        for (int u = 0; u < 8; ++u) h1T[(j0 + u) * H1STR + nl] = elu_f(a[u]);
    }
    __syncthreads();

    const int cg = t & 15;
    const int nq = t >> 4;
    const int c0 = cg * 4;
    float acc[4][4];
#pragma unroll
    for (int i = 0; i < 4; ++i)
#pragma unroll
        for (int c = 0; c < 4; ++c) acc[i][c] = b2s[c0 + c];
#pragma unroll 8
    for (int k = 0; k < 32; ++k) {
        const float4 hv = *(const float4*)(h1T + k * H1STR + nq * 4);
        const float4 wv = *(const float4*)(W2s + k * 64 + c0);
        const float hvv[4] = {hv.x, hv.y, hv.z, hv.w};
#pragma unroll
        for (int i = 0; i < 4; ++i) {
            acc[i][0] += hvv[i] * wv.x; acc[i][1] += hvv[i] * wv.y;
            acc[i][2] += hvv[i] * wv.z; acc[i][3] += hvv[i] * wv.w;
        }
    }
    float o[4][4];
#pragma unroll
    for (int i = 0; i < 4; ++i)
#pragma unroll
        for (int c = 0; c < 4; ++c) o[i][c] = elu_f(acc[i][c]);

#pragma unroll
    for (int i = 0; i < 4; ++i) {
        const int n = n0 + nq * 4 + i;
        if (n < n_nodes)
            *(float4*)(h0 + (size_t)n * 64 + c0) =
                make_float4(o[i][0], o[i][1], o[i][2], o[i][3]);
    }
    float ad[4][8];
#pragma unroll
    for (int i = 0; i < 4; ++i)
#pragma unroll
        for (int jj = 0; jj < 8; ++jj) ad[i][jj] = 0.f;
#pragma unroll
    for (int c = 0; c < 4; ++c) {
        const float4 v0 = *(const float4*)(vsd + (c0 + c) * 8);
        const float4 v1 = *(const float4*)(vsd + (c0 + c) * 8 + 4);
#pragma unroll
        for (int i = 0; i < 4; ++i) {
            ad[i][0] += o[i][c] * v0.x; ad[i][1] += o[i][c] * v0.y;
            ad[i][2] += o[i][c] * v0.z; ad[i][3] += o[i][c] * v0.w;
            ad[i][4] += o[i][c] * v1.x; ad[i][5] += o[i][c] * v1.y;
            ad[i][6] += o[i][c] * v1.z; ad[i][7] += o[i][c] * v1.w;
        }
    }
#pragma unroll
    for (int off = 1; off < 16; off <<= 1) {
#pragma unroll
        for (int i = 0; i < 4; ++i)
#pragma unroll
            for (int jj = 0; jj < 8; ++jj)
                ad[i][jj] += __shfl_xor(ad[i][jj], off);
    }
    if (cg == 0) {
#pragma unroll
        for (int i = 0; i < 4; ++i) {
            const int n = n0 + nq * 4 + i;
            if (n < n_nodes) {
#pragma unroll
                for (int h = 0; h < 4; ++h) {
                    asrc[n * 4 + h] = ad[i][h];
                    adst[n * 4 + h] = ad[i][4 + h];
                }
            }
        }
    }
}

// ---------------------------------------------------------------------------
// Fused GAT layer v4 (DS-instruction-minimized, R2 shape preserved):
// 32 nodes/block, 512 threads, 4 blocks/CU (LDS 35,328 B unchanged).
// Agg: per 16-edge chunk, lane q computes its OWN edge's 4 exp-weights + src
//   id and stores them in LDS (hosted inside the idle Wp buffer); the gather
//   loop does 2 same-address broadcast reads per edge (b128 + b32) instead of
//   5 ds_bpermute shuffles. den accumulated redundantly per lane (no reduce).
// GEMM: 4 nodes/thread on t<128 -> W-reads amortized 2x (1536 -> 1024 DS
//   wave-instrs/block). Results handed off via gS so epilogue keeps the
//   proven t<256 2-node shape.
// ---------------------------------------------------------------------------
#define GSTR 132
__global__ __launch_bounds__(512, 8) void gat_fused_kernel(
    const float* __restrict__ bin, const float* __restrict__ asrc,
    const float* __restrict__ adst, const int* __restrict__ rowptr,
    const int* __restrict__ col,
    const float* __restrict__ W, const float* __restrict__ bias,
    const float* __restrict__ vfold_next, int has_next,
    float* __restrict__ out,
    float* __restrict__ nasrc, float* __restrict__ nadst,
    const float* __restrict__ Wm1, const float* __restrict__ bm1,
    const float* __restrict__ Wm2, const float* __restrict__ bm2,
    const float* __restrict__ Wm3, const float* __restrict__ bm3,
    float* __restrict__ mlp_out, int n_nodes) {
    __shared__ float gS[32 * GSTR];   // 16,896 B
    __shared__ float Wp[4096];        // 16,384 B (hosts wE/sE during agg)
    __shared__ float vN[512];         //  2,048 B
    const int t = threadIdx.x;
    const int n0 = blockIdx.x * 32;
    const int grp = t >> 4;           // 0..31 : ONE node per group (agg)
    const int q = t & 15;             // lane in group
    const int c0 = q * 4;

    // edge-weight staging buffers inside Wp (free until GEMM staging):
    // wEf[(grp*17+j)*4 + h] : per-edge exp weights (stride 17 -> distinct
    // banks per group on broadcast reads). sEi[grp*17+j] : per-edge src id.
    float* wEf = Wp;                       // 2176 floats
    int*   sEi = (int*)(Wp + 2176);        //  544 ints

    if (has_next && t < 128) *(float4*)(vN + t * 4) = *(const float4*)(vfold_next + t * 4);

    // ============ phase 1: aggregation (1 node per 16-lane group) ============
    float keep[8];                    // normalized heads {2,3}
    {
        const int n = n0 + grp;
        float acc[4][4];
#pragma unroll
        for (int h = 0; h < 4; ++h)
#pragma unroll
            for (int z = 0; z < 4; ++z) acc[h][z] = 0.f;
        if (n < n_nodes) {
            float4 den4 = make_float4(0.f, 0.f, 0.f, 0.f);
            const float4 ad4 = *(const float4*)(adst + (size_t)n * 4);
            const int start = rowptr[n], end = rowptr[n + 1];
            for (int base = start; base < end; base += 16) {
                const int cnt = min(16, end - base);
                // phase A: lane q computes weights for its own edge base+q
                float4 w4 = make_float4(0.f, 0.f, 0.f, 0.f);
                int c = 0;
                if (base + q < end) {
                    c = col[base + q];
                    const float4 av = *(const float4*)(asrc + (size_t)c * 4);
                    float l0 = av.x + ad4.x; l0 = l0 > 0.f ? l0 : NEG_SLOPE * l0;
                    float l1 = av.y + ad4.y; l1 = l1 > 0.f ? l1 : NEG_SLOPE * l1;
                    float l2 = av.z + ad4.z; l2 = l2 > 0.f ? l2 : NEG_SLOPE * l2;
                    float l3 = av.w + ad4.w; l3 = l3 > 0.f ? l3 : NEG_SLOPE * l3;
                    w4.x = __expf(fminf(l0, 60.f));
                    w4.y = __expf(fminf(l1, 60.f));
                    w4.z = __expf(fminf(l2, 60.f));
                    w4.w = __expf(fminf(l3, 60.f));
                }
                *(float4*)(wEf + (grp * 17 + q) * 4) = w4;
                sEi[grp * 17 + q] = c;
                __builtin_amdgcn_sched_barrier(0);   // writes before reads (same wave)
                // phase B: broadcast-read weights, gather bin
#pragma unroll 4
                for (int j = 0; j < cnt; ++j) {
                    const float4 wj = *(const float4*)(wEf + (grp * 17 + j) * 4);
                    const int s = sEi[grp * 17 + j];
                    const float4 hv = *(const float4*)(bin + (size_t)s * 64 + q * 4);
                    den4.x += wj.x; den4.y += wj.y; den4.z += wj.z; den4.w += wj.w;
                    acc[0][0] += wj.x * hv.x; acc[0][1] += wj.x * hv.y;
                    acc[0][2] += wj.x * hv.z; acc[0][3] += wj.x * hv.w;
                    acc[1][0] += wj.y * hv.x; acc[1][1] += wj.y * hv.y;
                    acc[1][2] += wj.y * hv.z; acc[1][3] += wj.y * hv.w;
                    acc[2][0] += wj.z * hv.x; acc[2][1] += wj.z * hv.y;
                    acc[2][2] += wj.z * hv.z; acc[2][3] += wj.z * hv.w;
                    acc[3][0] += wj.w * hv.x; acc[3][1] += wj.w * hv.y;
                    acc[3][2] += wj.w * hv.z; acc[3][3] += wj.w * hv.w;
                }
                __builtin_amdgcn_sched_barrier(0);   // reads before next chunk's writes
            }
            // every lane holds the full denominator (accumulated from bcasts)
            const float i0 = 1.f / (den4.x + 1e-16f);
            const float i1 = 1.f / (den4.y + 1e-16f);
            const float i2 = 1.f / (den4.z + 1e-16f);
            const float i3 = 1.f / (den4.w + 1e-16f);
            *(float4*)(gS + grp * GSTR + c0) =
                make_float4(acc[0][0] * i0, acc[0][1] * i0, acc[0][2] * i0, acc[0][3] * i0);
            *(float4*)(gS + grp * GSTR + 64 + c0) =
                make_float4(acc[1][0] * i1, acc[1][1] * i1, acc[1][2] * i1, acc[1][3] * i1);
            keep[0] = acc[2][0] * i2; keep[1] = acc[2][1] * i2;
            keep[2] = acc[2][2] * i2; keep[3] = acc[2][3] * i2;
            keep[4] = acc[3][0] * i3; keep[5] = acc[3][1] * i3;
            keep[6] = acc[3][2] * i3; keep[7] = acc[3][3] * i3;
        } else {
            const float4 z4 = make_float4(0.f, 0.f, 0.f, 0.f);
            *(float4*)(gS + grp * GSTR + c0) = z4;
            *(float4*)(gS + grp * GSTR + 64 + c0) = z4;
#pragma unroll
            for (int u = 0; u < 8; ++u) keep[u] = 0.f;
        }
    }
    __syncthreads();   // agg done: gS complete, Wp (wE/sE) free for W staging

    // ============ phase 2: head-mean projection GEMM (t<128, 4 nodes/thr) ===
    const int ng4 = t >> 4;           // 0..7 when t<128 : nodes ng4*4 .. +3
    float ga[4][4];
#pragma unroll
    for (int i = 0; i < 4; ++i)
#pragma unroll
        for (int c = 0; c < 4; ++c) ga[i][c] = 0.f;

#pragma unroll
    for (int half = 0; half < 2; ++half) {
        if (half == 1) {
            // all GEMM reads of half-0 data done (post-slab sync): swap heads
            *(float4*)(gS + grp * GSTR + c0) =
                make_float4(keep[0], keep[1], keep[2], keep[3]);
            *(float4*)(gS + grp * GSTR + 64 + c0) =
                make_float4(keep[4], keep[5], keep[6], keep[7]);
        }
#pragma unroll
        for (int s = 0; s < 2; ++s) {
            // stage W slab (all 512 threads)
#pragma unroll
            for (int j = 0; j < 2; ++j) {
                const int f4 = j * 512 + t;
                const int kl = f4 >> 4;
                const int c = (f4 & 15) * 4;
                const int m = half * 128 + s * 64 + kl;
                const int h = m >> 6, kk = m & 63;
                *(float4*)(Wp + kl * 64 + c) = *(const float4*)(W + kk * 256 + h * 64 + c);
            }
            __syncthreads();
            if (t < 128) {
#pragma unroll 4
                for (int ks = 0; ks < 64; ks += 4) {
                    const float4 w0 = *(const float4*)(Wp + (ks + 0) * 64 + c0);
                    const float4 w1 = *(const float4*)(Wp + (ks + 1) * 64 + c0);
                    const float4 w2 = *(const float4*)(Wp + (ks + 2) * 64 + c0);
                    const float4 w3 = *(const float4*)(Wp + (ks + 3) * 64 + c0);
#pragma unroll
                    for (int i = 0; i < 4; ++i) {
                        const float4 a = *(const float4*)(gS + (ng4 * 4 + i) * GSTR + s * 64 + ks);
                        ga[i][0] += a.x * w0.x + a.y * w1.x + a.z * w2.x + a.w * w3.x;
                        ga[i][1] += a.x * w0.y + a.y * w1.y + a.z * w2.y + a.w * w3.y;
                        ga[i][2] += a.x * w0.z + a.y * w1.z + a.z * w2.z + a.w * w3.z;
                        ga[i][3] += a.x * w0.w + a.y * w1.w + a.z * w2.w + a.w * w3.w;
                    }
                }
            }
            __syncthreads();
        }
    }

    // handoff: GEMM results -> gS[node][col] (gS free after last k-loop sync)
    if (t < 128) {
#pragma unroll
        for (int i = 0; i < 4; ++i)
            *(float4*)(gS + (ng4 * 4 + i) * GSTR + c0) =
                make_float4(ga[i][0], ga[i][1], ga[i][2], ga[i][3]);
    }
    __syncthreads();

    // ============ epilogue: bias + head-mean + residual (t<256, 2 nodes) ====
    const int ng2 = t >> 4;           // valid when t<256
    float o[2][4];
    if (t < 256) {
        const float4 bb = *(const float4*)(bias + c0);
#pragma unroll
        for (int i = 0; i < 2; ++i) {
            const int n = n0 + ng2 * 2 + i;
            if (n < n_nodes) {
                const float4 g4 = *(const float4*)(gS + (ng2 * 2 + i) * GSTR + c0);
                const float4 x4 = *(const float4*)(bin + (size_t)n * 64 + c0);
                o[i][0] = 0.25f * g4.x + bb.x + x4.x;
                o[i][1] = 0.25f * g4.y + bb.y + x4.y;
                o[i][2] = 0.25f * g4.z + bb.z + x4.z;
                o[i][3] = 0.25f * g4.w + bb.w + x4.w;
                if (has_next)
                    *(float4*)(out + (size_t)n * 64 + c0) =
                        make_float4(o[i][0], o[i][1], o[i][2], o[i][3]);
            } else {
                o[i][0] = o[i][1] = o[i][2] = o[i][3] = 0.f;
            }
        }
    } else {
#pragma unroll
        for (int i = 0; i < 2; ++i)
            o[i][0] = o[i][1] = o[i][2] = o[i][3] = 0.f;
    }

    if (has_next) {
        if (t < 256) {
            float pj[2][8];
#pragma unroll
            for (int i = 0; i < 2; ++i)
#pragma unroll
                for (int jj = 0; jj < 8; ++jj) pj[i][jj] = 0.f;
#pragma unroll
            for (int c = 0; c < 4; ++c) {
                const float4 v0 = *(const float4*)(vN + (c0 + c) * 8);
                const float4 v1 = *(const float4*)(vN + (c0 + c) * 8 + 4);
#pragma unroll
                for (int i = 0; i < 2; ++i) {
                    pj[i][0] += o[i][c] * v0.x; pj[i][1] += o[i][c] * v0.y;
                    pj[i][2] += o[i][c] * v0.z; pj[i][3] += o[i][c] * v0.w;
                    pj[i][4] += o[i][c] * v1.x; pj[i][5] += o[i][c] * v1.y;
                    pj[i][6] += o[i][c] * v1.z; pj[i][7] += o[i][c] * v1.w;
                }
            }
#pragma unroll
            for (int off = 1; off < 16; off <<= 1) {
#pragma unroll
                for (int i = 0; i < 2; ++i)
#pragma unroll
                    for (int jj = 0; jj < 8; ++jj)
                        pj[i][jj] += __shfl_xor(pj[i][jj], off);
            }
            if (q == 0) {
#pragma unroll
                for (int i = 0; i < 2; ++i) {
                    const int n = n0 + ng2 * 2 + i;
                    if (n < n_nodes) {
#pragma unroll
                        for (int h = 0; h < 4; ++h) {
                            nasrc[n * 4 + h] = pj[i][h];
                            nadst[n * 4 + h] = pj[i][4 + h];
                        }
                    }
                }
            }
        }
        return;
    }

    // ============ fused output MLP 64->64->32->8 (last layer, 32 nodes) =====
    if (t < 256) {
#pragma unroll
        for (int i = 0; i < 2; ++i)
            *(float4*)(gS + (ng2 * 2 + i) * GSTR + c0) =
                make_float4(o[i][0], o[i][1], o[i][2], o[i][3]);
    }
#pragma unroll
    for (int j = 0; j < 2; ++j)
        *(float4*)(Wp + (j * 512 + t) * 4) = *(const float4*)(Wm1 + (j * 512 + t) * 4);
    if (t < 64) vN[t] = bm1[t];
    else if (t < 96) vN[t] = bm2[t - 64];
    else if (t < 104) vN[t] = bm3[t - 96];
    if (t < 256) vN[104 + t] = Wm3[t];
    __syncthreads();
    // MLP1: 32 nodes x 64 cols, thread (t<256) = 1 node x 8 cols
    if (t < 256) {
        const int ng = t >> 3;            // 0..31
        const int cm0 = (t & 7) * 8;
        float a1[8];
#pragma unroll
        for (int u = 0; u < 8; ++u) a1[u] = vN[cm0 + u];
#pragma unroll 4
        for (int k = 0; k < 64; ++k) {
            const float hv = gS[ng * GSTR + k];
            const float4 w0 = *(const float4*)(Wp + k * 64 + cm0);
            const float4 w1 = *(const float4*)(Wp + k * 64 + cm0 + 4);
            a1[0] += hv * w0.x; a1[1] += hv * w0.y;
            a1[2] += hv * w0.z; a1[3] += hv * w0.w;
            a1[4] += hv * w1.x; a1[5] += hv * w1.y;
            a1[6] += hv * w1.z; a1[7] += hv * w1.w;
        }
        *(float4*)(gS + ng * GSTR + 64 + cm0) =
            make_float4(elu_f(a1[0]), elu_f(a1[1]), elu_f(a1[2]), elu_f(a1[3]));
        *(float4*)(gS + ng * GSTR + 64 + cm0 + 4) =
            make_float4(elu_f(a1[4]), elu_f(a1[5]), elu_f(a1[6]), elu_f(a1[7]));
    }
    __syncthreads();
    *(float4*)(Wp + t * 4) = *(const float4*)(Wm2 + t * 4);
    __syncthreads();
    // MLP2: 32 nodes x 32 cols, thread (t<256) = 1 node x 4 cols
    if (t < 256) {
        const int nn = t >> 3;            // 0..31
        const int cc0 = (t & 7) * 4;
        float a2[4];
#pragma unroll
        for (int u = 0; u < 4; ++u) a2[u] = vN[64 + cc0 + u];
#pragma unroll 4
        for (int j = 0; j < 64; ++j) {
            const float ov = gS[nn * GSTR + 64 + j];
            const float4 w = *(const float4*)(Wp + j * 32 + cc0);
            a2[0] += ov * w.x; a2[1] += ov * w.y;
            a2[2] += ov * w.z; a2[3] += ov * w.w;
        }
        __syncthreads();
        *(float4*)(gS + nn * GSTR + cc0) =
            make_float4(elu_f(a2[0]), elu_f(a2[1]), elu_f(a2[2]), elu_f(a2[3]));
    } else {
        __syncthreads();
    }
    __syncthreads();
    // MLP3: 32 nodes x 8 cols, thread (t<256) = 1 output
    if (t < 256) {
        const int nl = t >> 3;
        const int c3 = t & 7;
        const int n = n0 + nl;
        if (n < n_nodes) {
            float a3 = vN[96 + c3];
#pragma unroll 4
            for (int j = 0; j < 32; ++j)
                a3 += gS[nl * GSTR + j] * vN[104 + j * 8 + c3];
            mlp_out[(size_t)n * 8 + c3] = a3;
        }
    }
}

// ---------------------------------------------------------------------------
extern "C" void kernel_launch(void* const* d_in, const int* in_sizes, int n_in,
                              void* d_out, int out_size, void* d_ws, size_t ws_size,
                              hipStream_t stream) {
    const float* x     = (const float*)d_in[0];
    const int*   ei    = (const int*)d_in[1];
    const float* Wenc1 = (const float*)d_in[2];
    const float* benc1 = (const float*)d_in[3];
    const float* Wenc2 = (const float*)d_in[4];
    const float* benc2 = (const float*)d_in[5];
    const float* Wg[3]  = {(const float*)d_in[6],  (const float*)d_in[10], (const float*)d_in[14]};
    const float* as_[3] = {(const float*)d_in[7],  (const float*)d_in[11], (const float*)d_in[15]};
    const float* ad_[3] = {(const float*)d_in[8],  (const float*)d_in[12], (const float*)d_in[16]};
    const float* bg[3]  = {(const float*)d_in[9],  (const float*)d_in[13], (const float*)d_in[17]};
    const float* Wo1 = (const float*)d_in[18];
    const float* bo1 = (const float*)d_in[19];
    const float* Wo2 = (const float*)d_in[20];
    const float* bo2 = (const float*)d_in[21];
    const float* Wo3 = (const float*)d_in[22];
    const float* bo3 = (const float*)d_in[23];

    const int N = in_sizes[0] / 8;
    const int E = in_sizes[1] / 2;
    const int Etot = E + N;
    const int nblk = (N + SCAN_B - 1) / SCAN_B;  // 79
    const int FB = (Etot + 255) / 256;
    const int NB64 = (N + 63) / 64;
    const int NB32 = (N + 31) / 32;

    float* buf0  = (float*)d_ws;                  // N*64
    float* buf1  = buf0 + (size_t)N * 64;         // N*64
    float* asA   = buf1 + (size_t)N * 64;         // N*4
    float* adA   = asA + (size_t)N * 4;           // N*4
    float* asB   = adA + (size_t)N * 4;           // N*4
    float* adB   = asB + (size_t)N * 4;           // N*4
    float* vfold = adB + (size_t)N * 4;           // 3*512
    int* rowptr = (int*)(vfold + 3 * 512);        // N+1 (+pad)
    int* cursor = rowptr + (N + 2);               // N
    int* cnt    = cursor + N;                     // N
    int* ready  = cnt + N;                        // 128
    int* flag   = ready + 128;                    // 1 (+pad)
    int* col    = flag + 2;                       // Etot

    prep_kernel<<<nblk + 6, 256, 0, stream>>>(ei,
        Wg[0], as_[0], ad_[0], Wg[1], as_[1], ad_[1], Wg[2], as_[2], ad_[2],
        cnt, ready, flag, vfold, N);
    count_kernel<<<(Etot + 255) / 256, 256, 0, stream>>>(ei, flag, E, Etot, cnt);
    scan_onepass_kernel<<<nblk, SCAN_B, 0, stream>>>(cnt, ready, rowptr, cursor, N);
    fillenc_kernel<<<FB + NB64, 256, 0, stream>>>(ei, flag, E, Etot, cursor, col, FB,
                                                  x, Wenc1, benc1, Wenc2, benc2,
                                                  vfold, buf0, asA, adA, N);

    // layer 0: read dots A, write dots B
    gat_fused_kernel<<<NB32, 512, 0, stream>>>(
        buf0, asA, adA, rowptr, col, Wg[0], bg[0], vfold + 512, 1,
        buf1, asB, adB, Wo1, bo1, Wo2, bo2, Wo3, bo3, (float*)d_out, N);
    // layer 1: read dots B, write dots A
    gat_fused_kernel<<<NB32, 512, 0, stream>>>(
        buf1, asB, adB, rowptr, col, Wg[1], bg[1], vfold + 1024, 1,
        buf0, asA, adA, Wo1, bo1, Wo2, bo2, Wo3, bo3, (float*)d_out, N);
    // layer 2: read dots A, fused output MLP -> d_out
    gat_fused_kernel<<<NB32, 512, 0, stream>>>(
        buf0, asA, adA, rowptr, col, Wg[2], bg[2], vfold, 0,
        buf1, asB, adB, Wo1, bo1, Wo2, bo2, Wo3, bo3, (float*)d_out, N);
}

// Round 12
// 324.252 us; speedup vs baseline: 1.0082x; 1.0082x over previous
//
#include <hip/hip_runtime.h>
#include <cstdint>
#include <cstddef>

#define NEG_SLOPE 0.2f

__device__ __forceinline__ float elu_f(float x) {
    return x > 0.f ? x : expm1f(x);
}

// ---------------------------------------------------------------------------
// P0: zero cnt + ready, detect edge-index layout, compute folded attention
// vectors for all 3 layers. Blocks 0..78 zero; blocks 79..84 fold.
// vfold[l][k*8+j] = sum_cc W_l[k, h*64+cc]*att[h,cc] (j<4 src, j>=4 dst, h=j&3)
// ---------------------------------------------------------------------------
__global__ __launch_bounds__(256) void prep_kernel(
    const int* __restrict__ ei,
    const float* __restrict__ W0, const float* __restrict__ as0, const float* __restrict__ ad0,
    const float* __restrict__ W1, const float* __restrict__ as1, const float* __restrict__ ad1,
    const float* __restrict__ W2, const float* __restrict__ as2, const float* __restrict__ ad2,
    int* __restrict__ cnt, int* __restrict__ ready, int* __restrict__ flag,
    float* __restrict__ vfold, int n) {
    const int b = blockIdx.x, t = threadIdx.x;
    if (b < 79) {
        const int i = b * 256 + t;
        if (i < n) cnt[i] = 0;
        if (b == 0) {
            if (t < 128) ready[t] = 0;
            if (t == 0) {
                int acc = 0;
#pragma unroll
                for (int k = 0; k < 8; ++k) acc |= ei[2 * k + 1];
                flag[0] = (acc == 0) ? 1 : 0;
            }
        }
        return;
    }
    const int e = (b - 79) * 256 + t;
    if (e >= 1536) return;
    const int l = e >> 9, rem = e & 511;
    const int k = rem >> 3, j = rem & 7, h = j & 3;
    const float* W   = (l == 0) ? W0  : (l == 1) ? W1  : W2;
    const float* as_ = (l == 0) ? as0 : (l == 1) ? as1 : as2;
    const float* ad_ = (l == 0) ? ad0 : (l == 1) ? ad1 : ad2;
    const float* av = (j < 4) ? as_ : ad_;
    const float* wr = W + k * 256 + h * 64;
    const float* ar = av + h * 64;
    float s = 0.f;
#pragma unroll 8
    for (int cc = 0; cc < 64; ++cc) s += wr[cc] * ar[cc];
    vfold[l * 512 + k * 8 + j] = s;
}

__global__ void count_kernel(const int* __restrict__ ei, const int* __restrict__ flag,
                             int E, int Etot, int* __restrict__ cnt) {
    int e = blockIdx.x * blockDim.x + threadIdx.x;
    if (e >= Etot) return;
    int d;
    if (e < E) d = flag[0] ? ei[2 * (size_t)(E + e)] : ei[E + e];
    else       d = e - E;  // self loop
    atomicAdd(&cnt[d], 1);
}

// ---------------------------------------------------------------------------
// One-pass scan with parallel lookback (79 co-resident blocks).
// ---------------------------------------------------------------------------
#define SCAN_B 256
__global__ __launch_bounds__(256) void scan_onepass_kernel(
    const int* __restrict__ cnt, int* __restrict__ ready,
    int* __restrict__ rowptr, int* __restrict__ cursor, int n) {
    __shared__ int sd[SCAN_B];
    __shared__ int sred[128];
    __shared__ int s_pref;
    const int b = blockIdx.x, t = threadIdx.x;
    const int g = b * SCAN_B + t;
    const int v = (g < n) ? cnt[g] : 0;
    sd[t] = v;
    __syncthreads();
    for (int off = 1; off < SCAN_B; off <<= 1) {
        int add = (t >= off) ? sd[t - off] : 0;
        __syncthreads();
        sd[t] += add;
        __syncthreads();
    }
    if (t == SCAN_B - 1) atomicExch(&ready[b], sd[SCAN_B - 1] + 1);
    if (t < 128) {
        int pv = 0;
        if (t < b) {
            do { pv = atomicAdd(&ready[t], 0); __builtin_amdgcn_s_sleep(1); } while (pv == 0);
            pv -= 1;
        }
        sred[t] = pv;
    }
    __syncthreads();
    if (t == 0) {
        int s = 0;
#pragma unroll 8
        for (int i = 0; i < 128; ++i) s += sred[i];
        s_pref = s;
    }
    __syncthreads();
    const int pre = s_pref;
    if (g < n) {
        const int e = pre + sd[t];
        rowptr[g + 1] = e;
        cursor[g] = e - v;
        if (g == 0) rowptr[0] = 0;
    }
}

// ---------------------------------------------------------------------------
// fill (CSR scatter) + encoder merged into one dispatch: blocks [0,FB) do the
// CSR fill, blocks [FB, FB+ceil(N/64)) run the encoder.
// ---------------------------------------------------------------------------
#define H1STR 68
__global__ __launch_bounds__(256) void fillenc_kernel(
    const int* __restrict__ ei, const int* __restrict__ flag,
    int E, int Etot, int* __restrict__ cursor, int* __restrict__ col, int FB,
    const float* __restrict__ x,
    const float* __restrict__ W1, const float* __restrict__ b1,
    const float* __restrict__ W2, const float* __restrict__ b2,
    const float* __restrict__ vfold0,
    float* __restrict__ h0, float* __restrict__ asrc, float* __restrict__ adst,
    int n_nodes) {
    if (blockIdx.x < FB) {
        const int e = blockIdx.x * 256 + threadIdx.x;
        if (e >= Etot) return;
        int s, d;
        if (e < E) {
            if (flag[0]) { s = ei[2 * (size_t)e]; d = ei[2 * (size_t)(E + e)]; }
            else         { s = ei[e];             d = ei[E + e]; }
        } else {
            s = d = e - E;
        }
        int pos = atomicAdd(&cursor[d], 1);
        col[pos] = s;
        return;
    }
    __shared__ float W1s[256];
    __shared__ float b1s[32];
    __shared__ float W2s[2048];
    __shared__ float b2s[64];
    __shared__ float vsd[512];
    __shared__ float xS[512];            // 64 nodes x 8
    __shared__ float h1T[32 * H1STR];    // [k][node]
    const int t = threadIdx.x;
    const int n0 = (blockIdx.x - FB) * 64;
    const int rem = n_nodes - n0;

    *(float4*)(W2s + t * 4) = *(const float4*)(W2 + t * 4);
    *(float4*)(W2s + 1024 + t * 4) = *(const float4*)(W2 + 1024 + t * 4);
    if (t < 64)  *(float4*)(W1s + t * 4) = *(const float4*)(W1 + t * 4);
    if (t < 8)   *(float4*)(b1s + t * 4) = *(const float4*)(b1 + t * 4);
    if (t < 16)  *(float4*)(b2s + t * 4) = *(const float4*)(b2 + t * 4);
    if (t < 128) *(float4*)(vsd + t * 4) = *(const float4*)(vfold0 + t * 4);
    if (t < 128) {
        const int fidx = t * 4;
        float4 v = make_float4(0.f, 0.f, 0.f, 0.f);
        if (fidx < rem * 8) v = *(const float4*)(x + (size_t)n0 * 8 + fidx);
        *(float4*)(xS + fidx) = v;
    }
    __syncthreads();

    {
        const int nl = t >> 2;
        const int j0 = (t & 3) * 8;
        const float4 xa = *(const float4*)(xS + nl * 8);
        const float4 xb = *(const float4*)(xS + nl * 8 + 4);
        const float xk[8] = {xa.x, xa.y, xa.z, xa.w, xb.x, xb.y, xb.z, xb.w};
        float a[8];
#pragma unroll
        for (int u = 0; u < 8; ++u) a[u] = b1s[j0 + u];
#pragma unroll
        for (int k = 0; k < 8; ++k) {
            const float4 w0 = *(const float4*)(W1s + k * 32 + j0);
            const float4 w1 = *(const float4*)(W1s + k * 32 + j0 + 4);
            a[0] += xk[k] * w0.x; a[1] += xk[k] * w0.y;
            a[2] += xk[k] * w0.z; a[3] += xk[k] * w0.w;
            a[4] += xk[k] * w1.x; a[5] += xk[k] * w1.y;
            a[6] += xk[k] * w1.z; a[7] += xk[k] * w1.w;
        }
#pragma unroll
        for (int u = 0; u < 8; ++u) h1T[(j0 + u) * H1STR + nl] = elu_f(a[u]);
    }
    __syncthreads();

    const int cg = t & 15;
    const int nq = t >> 4;
    const int c0 = cg * 4;
    float acc[4][4];
#pragma unroll
    for (int i = 0; i < 4; ++i)
#pragma unroll
        for (int c = 0; c < 4; ++c) acc[i][c] = b2s[c0 + c];
#pragma unroll 8
    for (int k = 0; k < 32; ++k) {
        const float4 hv = *(const float4*)(h1T + k * H1STR + nq * 4);
        const float4 wv = *(const float4*)(W2s + k * 64 + c0);
        const float hvv[4] = {hv.x, hv.y, hv.z, hv.w};
#pragma unroll
        for (int i = 0; i < 4; ++i) {
            acc[i][0] += hvv[i] * wv.x; acc[i][1] += hvv[i] * wv.y;
            acc[i][2] += hvv[i] * wv.z; acc[i][3] += hvv[i] * wv.w;
        }
    }
    float o[4][4];
#pragma unroll
    for (int i = 0; i < 4; ++i)
#pragma unroll
        for (int c = 0; c < 4; ++c) o[i][c] = elu_f(acc[i][c]);

#pragma unroll
    for (int i = 0; i < 4; ++i) {
        const int n = n0 + nq * 4 + i;
        if (n < n_nodes)
            *(float4*)(h0 + (size_t)n * 64 + c0) =
                make_float4(o[i][0], o[i][1], o[i][2], o[i][3]);
    }
    float ad[4][8];
#pragma unroll
    for (int i = 0; i < 4; ++i)
#pragma unroll
        for (int jj = 0; jj < 8; ++jj) ad[i][jj] = 0.f;
#pragma unroll
    for (int c = 0; c < 4; ++c) {
        const float4 v0 = *(const float4*)(vsd + (c0 + c) * 8);
        const float4 v1 = *(const float4*)(vsd + (c0 + c) * 8 + 4);
#pragma unroll
        for (int i = 0; i < 4; ++i) {
            ad[i][0] += o[i][c] * v0.x; ad[i][1] += o[i][c] * v0.y;
            ad[i][2] += o[i][c] * v0.z; ad[i][3] += o[i][c] * v0.w;
            ad[i][4] += o[i][c] * v1.x; ad[i][5] += o[i][c] * v1.y;
            ad[i][6] += o[i][c] * v1.z; ad[i][7] += o[i][c] * v1.w;
        }
    }
#pragma unroll
    for (int off = 1; off < 16; off <<= 1) {
#pragma unroll
        for (int i = 0; i < 4; ++i)
#pragma unroll
            for (int jj = 0; jj < 8; ++jj)
                ad[i][jj] += __shfl_xor(ad[i][jj], off);
    }
    if (cg == 0) {
#pragma unroll
        for (int i = 0; i < 4; ++i) {
            const int n = n0 + nq * 4 + i;
            if (n < n_nodes) {
#pragma unroll
                for (int h = 0; h < 4; ++h) {
                    asrc[n * 4 + h] = ad[i][h];
                    adst[n * 4 + h] = ad[i][4 + h];
                }
            }
        }
    }
}

// ---------------------------------------------------------------------------
// Fused GAT layer v5 (single change vs the measured 281.8us R2 baseline):
// R2's proven shuffle aggregation + GEMM reblock: t<128, 4 nodes/thread so
// each W ds_read amortizes over 4 nodes (1536 -> ~1030 DS wave-instrs/block
// on the DS-saturated GEMM phase). 32 nodes/block, 625 blocks, 512 threads,
// 4 blocks/CU (LDS 35,328 B unchanged).
// ---------------------------------------------------------------------------
#define GSTR 132
__global__ __launch_bounds__(512, 8) void gat_fused_kernel(
    const float* __restrict__ bin, const float* __restrict__ asrc,
    const float* __restrict__ adst, const int* __restrict__ rowptr,
    const int* __restrict__ col,
    const float* __restrict__ W, const float* __restrict__ bias,
    const float* __restrict__ vfold_next, int has_next,
    float* __restrict__ out,
    float* __restrict__ nasrc, float* __restrict__ nadst,
    const float* __restrict__ Wm1, const float* __restrict__ bm1,
    const float* __restrict__ Wm2, const float* __restrict__ bm2,
    const float* __restrict__ Wm3, const float* __restrict__ bm3,
    float* __restrict__ mlp_out, int n_nodes) {
    __shared__ float gS[32 * GSTR];   // 16,896 B
    __shared__ float Wp[4096];        // 16,384 B
    __shared__ float vN[512];         //  2,048 B
    const int t = threadIdx.x;
    const int n0 = blockIdx.x * 32;
    const int grp = t >> 4;           // 0..31 : ONE node per group (agg)
    const int q = t & 15;             // lane in group
    const int c0 = q * 4;

    if (has_next && t < 128) *(float4*)(vN + t * 4) = *(const float4*)(vfold_next + t * 4);

    // ============ phase 1: aggregation (R2 shuffle form, unchanged) ==========
    float keep[8];                    // normalized heads {2,3}
    {
        const int n = n0 + grp;
        float acc[4][4];
#pragma unroll
        for (int h = 0; h < 4; ++h)
#pragma unroll
            for (int z = 0; z < 4; ++z) acc[h][z] = 0.f;
        if (n < n_nodes) {
            float4 den4 = make_float4(0.f, 0.f, 0.f, 0.f);
            const float4 ad4 = *(const float4*)(adst + (size_t)n * 4);
            const int start = rowptr[n], end = rowptr[n + 1];
            for (int base = start; base < end; base += 16) {
                const int cnt = min(16, end - base);
                int c = 0;
                float4 w4 = make_float4(0.f, 0.f, 0.f, 0.f);
                if (base + q < end) {
                    c = col[base + q];
                    const float4 av = *(const float4*)(asrc + (size_t)c * 4);
                    float l0 = av.x + ad4.x; l0 = l0 > 0.f ? l0 : NEG_SLOPE * l0;
                    float l1 = av.y + ad4.y; l1 = l1 > 0.f ? l1 : NEG_SLOPE * l1;
                    float l2 = av.z + ad4.z; l2 = l2 > 0.f ? l2 : NEG_SLOPE * l2;
                    float l3 = av.w + ad4.w; l3 = l3 > 0.f ? l3 : NEG_SLOPE * l3;
                    w4.x = __expf(fminf(l0, 60.f));
                    w4.y = __expf(fminf(l1, 60.f));
                    w4.z = __expf(fminf(l2, 60.f));
                    w4.w = __expf(fminf(l3, 60.f));
                    den4.x += w4.x; den4.y += w4.y; den4.z += w4.z; den4.w += w4.w;
                }
                int j = 0;
                for (; j + 4 <= cnt; j += 4) {
#pragma unroll
                    for (int u = 0; u < 4; ++u) {
                        const int s = __shfl(c, j + u, 16);
                        const float4 hv = *(const float4*)(bin + (size_t)s * 64 + q * 4);
                        const float wx = __shfl(w4.x, j + u, 16);
                        const float wy = __shfl(w4.y, j + u, 16);
                        const float wz = __shfl(w4.z, j + u, 16);
                        const float ww = __shfl(w4.w, j + u, 16);
                        acc[0][0] += wx * hv.x; acc[0][1] += wx * hv.y;
                        acc[0][2] += wx * hv.z; acc[0][3] += wx * hv.w;
                        acc[1][0] += wy * hv.x; acc[1][1] += wy * hv.y;
                        acc[1][2] += wy * hv.z; acc[1][3] += wy * hv.w;
                        acc[2][0] += wz * hv.x; acc[2][1] += wz * hv.y;
                        acc[2][2] += wz * hv.z; acc[2][3] += wz * hv.w;
                        acc[3][0] += ww * hv.x; acc[3][1] += ww * hv.y;
                        acc[3][2] += ww * hv.z; acc[3][3] += ww * hv.w;
                    }
                }
                for (; j < cnt; ++j) {
                    const int s = __shfl(c, j, 16);
                    const float4 hv = *(const float4*)(bin + (size_t)s * 64 + q * 4);
                    const float wx = __shfl(w4.x, j, 16);
                    const float wy = __shfl(w4.y, j, 16);
                    const float wz = __shfl(w4.z, j, 16);
                    const float ww = __shfl(w4.w, j, 16);
                    acc[0][0] += wx * hv.x; acc[0][1] += wx * hv.y;
                    acc[0][2] += wx * hv.z; acc[0][3] += wx * hv.w;
                    acc[1][0] += wy * hv.x; acc[1][1] += wy * hv.y;
                    acc[1][2] += wy * hv.z; acc[1][3] += wy * hv.w;
                    acc[2][0] += wz * hv.x; acc[2][1] += wz * hv.y;
                    acc[2][2] += wz * hv.z; acc[2][3] += wz * hv.w;
                    acc[3][0] += ww * hv.x; acc[3][1] += ww * hv.y;
                    acc[3][2] += ww * hv.z; acc[3][3] += ww * hv.w;
                }
            }
#pragma unroll
            for (int off = 1; off < 16; off <<= 1) {
                den4.x += __shfl_xor(den4.x, off, 16);
                den4.y += __shfl_xor(den4.y, off, 16);
                den4.z += __shfl_xor(den4.z, off, 16);
                den4.w += __shfl_xor(den4.w, off, 16);
            }
            const float i0 = 1.f / (den4.x + 1e-16f);
            const float i1 = 1.f / (den4.y + 1e-16f);
            const float i2 = 1.f / (den4.z + 1e-16f);
            const float i3 = 1.f / (den4.w + 1e-16f);
            *(float4*)(gS + grp * GSTR + c0) =
                make_float4(acc[0][0] * i0, acc[0][1] * i0, acc[0][2] * i0, acc[0][3] * i0);
            *(float4*)(gS + grp * GSTR + 64 + c0) =
                make_float4(acc[1][0] * i1, acc[1][1] * i1, acc[1][2] * i1, acc[1][3] * i1);
            keep[0] = acc[2][0] * i2; keep[1] = acc[2][1] * i2;
            keep[2] = acc[2][2] * i2; keep[3] = acc[2][3] * i2;
            keep[4] = acc[3][0] * i3; keep[5] = acc[3][1] * i3;
            keep[6] = acc[3][2] * i3; keep[7] = acc[3][3] * i3;
        } else {
            const float4 z4 = make_float4(0.f, 0.f, 0.f, 0.f);
            *(float4*)(gS + grp * GSTR + c0) = z4;
            *(float4*)(gS + grp * GSTR + 64 + c0) = z4;
#pragma unroll
            for (int u = 0; u < 8; ++u) keep[u] = 0.f;
        }
    }
    __syncthreads();   // agg gS writes visible before GEMM

    // ============ phase 2: head-mean GEMM (t<128, 4 nodes/thread) ============
    const int ng4 = t >> 4;           // 0..7 when t<128 : nodes ng4*4 .. +3
    float ga[4][4];
#pragma unroll
    for (int i = 0; i < 4; ++i)
#pragma unroll
        for (int c = 0; c < 4; ++c) ga[i][c] = 0.f;

#pragma unroll
    for (int half = 0; half < 2; ++half) {
        if (half == 1) {
            // all half-0 reads done (post-slab sync): swap heads {2,3} in
            *(float4*)(gS + grp * GSTR + c0) =
                make_float4(keep[0], keep[1], keep[2], keep[3]);
            *(float4*)(gS + grp * GSTR + 64 + c0) =
                make_float4(keep[4], keep[5], keep[6], keep[7]);
        }
#pragma unroll
        for (int s = 0; s < 2; ++s) {
            // stage W slab (all 512 threads)
#pragma unroll
            for (int j = 0; j < 2; ++j) {
                const int f4 = j * 512 + t;
                const int kl = f4 >> 4;
                const int c = (f4 & 15) * 4;
                const int m = half * 128 + s * 64 + kl;
                const int h = m >> 6, kk = m & 63;
                *(float4*)(Wp + kl * 64 + c) = *(const float4*)(W + kk * 256 + h * 64 + c);
            }
            __syncthreads();
            if (t < 128) {
#pragma unroll 4
                for (int ks = 0; ks < 64; ks += 4) {
                    const float4 w0 = *(const float4*)(Wp + (ks + 0) * 64 + c0);
                    const float4 w1 = *(const float4*)(Wp + (ks + 1) * 64 + c0);
                    const float4 w2 = *(const float4*)(Wp + (ks + 2) * 64 + c0);
                    const float4 w3 = *(const float4*)(Wp + (ks + 3) * 64 + c0);
#pragma unroll
                    for (int i = 0; i < 4; ++i) {
                        const float4 a = *(const float4*)(gS + (ng4 * 4 + i) * GSTR + s * 64 + ks);
                        ga[i][0] += a.x * w0.x + a.y * w1.x + a.z * w2.x + a.w * w3.x;
                        ga[i][1] += a.x * w0.y + a.y * w1.y + a.z * w2.y + a.w * w3.y;
                        ga[i][2] += a.x * w0.z + a.y * w1.z + a.z * w2.z + a.w * w3.z;
                        ga[i][3] += a.x * w0.w + a.y * w1.w + a.z * w2.w + a.w * w3.w;
                    }
                }
            }
            __syncthreads();
        }
    }

    // handoff: GEMM results -> gS[node][col] (gS free after last k-loop sync)
    if (t < 128) {
#pragma unroll
        for (int i = 0; i < 4; ++i)
            *(float4*)(gS + (ng4 * 4 + i) * GSTR + c0) =
                make_float4(ga[i][0], ga[i][1], ga[i][2], ga[i][3]);
    }
    __syncthreads();

    // ============ epilogue: bias + head-mean + residual (t<256) ============
    const int ng2 = t >> 4;           // valid when t<256
    float o[2][4];
    if (t < 256) {
        const float4 bb = *(const float4*)(bias + c0);
#pragma unroll
        for (int i = 0; i < 2; ++i) {
            const int n = n0 + ng2 * 2 + i;
            if (n < n_nodes) {
                const float4 g4 = *(const float4*)(gS + (ng2 * 2 + i) * GSTR + c0);
                const float4 x4 = *(const float4*)(bin + (size_t)n * 64 + c0);
                o[i][0] = 0.25f * g4.x + bb.x + x4.x;
                o[i][1] = 0.25f * g4.y + bb.y + x4.y;
                o[i][2] = 0.25f * g4.z + bb.z + x4.z;
                o[i][3] = 0.25f * g4.w + bb.w + x4.w;
                if (has_next)
                    *(float4*)(out + (size_t)n * 64 + c0) =
                        make_float4(o[i][0], o[i][1], o[i][2], o[i][3]);
            } else {
                o[i][0] = o[i][1] = o[i][2] = o[i][3] = 0.f;
            }
        }
    } else {
#pragma unroll
        for (int i = 0; i < 2; ++i)
            o[i][0] = o[i][1] = o[i][2] = o[i][3] = 0.f;
    }

    if (has_next) {
        if (t < 256) {
            float pj[2][8];
#pragma unroll
            for (int i = 0; i < 2; ++i)
#pragma unroll
                for (int jj = 0; jj < 8; ++jj) pj[i][jj] = 0.f;
#pragma unroll
            for (int c = 0; c < 4; ++c) {
                const float4 v0 = *(const float4*)(vN + (c0 + c) * 8);
                const float4 v1 = *(const float4*)(vN + (c0 + c) * 8 + 4);
#pragma unroll
                for (int i = 0; i < 2; ++i) {
                    pj[i][0] += o[i][c] * v0.x; pj[i][1] += o[i][c] * v0.y;
                    pj[i][2] += o[i][c] * v0.z; pj[i][3] += o[i][c] * v0.w;
                    pj[i][4] += o[i][c] * v1.x; pj[i][5] += o[i][c] * v1.y;
                    pj[i][6] += o[i][c] * v1.z; pj[i][7] += o[i][c] * v1.w;
                }
            }
#pragma unroll
            for (int off = 1; off < 16; off <<= 1) {
#pragma unroll
                for (int i = 0; i < 2; ++i)
#pragma unroll
                    for (int jj = 0; jj < 8; ++jj)
                        pj[i][jj] += __shfl_xor(pj[i][jj], off);
            }
            if (q == 0) {
#pragma unroll
                for (int i = 0; i < 2; ++i) {
                    const int n = n0 + ng2 * 2 + i;
                    if (n < n_nodes) {
#pragma unroll
                        for (int h = 0; h < 4; ++h) {
                            nasrc[n * 4 + h] = pj[i][h];
                            nadst[n * 4 + h] = pj[i][4 + h];
                        }
                    }
                }
            }
        }
        return;
    }

    // ============ fused output MLP 64->64->32->8 (last layer, 32 nodes) =====
    if (t < 256) {
#pragma unroll
        for (int i = 0; i < 2; ++i)
            *(float4*)(gS + (ng2 * 2 + i) * GSTR + c0) =
                make_float4(o[i][0], o[i][1], o[i][2], o[i][3]);
    }
#pragma unroll
    for (int j = 0; j < 2; ++j)
        *(float4*)(Wp + (j * 512 + t) * 4) = *(const float4*)(Wm1 + (j * 512 + t) * 4);
    if (t < 64) vN[t] = bm1[t];
    else if (t < 96) vN[t] = bm2[t - 64];
    else if (t < 104) vN[t] = bm3[t - 96];
    if (t < 256) vN[104 + t] = Wm3[t];
    __syncthreads();
    // MLP1: 32 nodes x 64 cols, thread (t<256) = 1 node x 8 cols
    if (t < 256) {
        const int ng = t >> 3;            // 0..31
        const int cm0 = (t & 7) * 8;
        float a1[8];
#pragma unroll
        for (int u = 0; u < 8; ++u) a1[u] = vN[cm0 + u];
#pragma unroll 4
        for (int k = 0; k < 64; ++k) {
            const float hv = gS[ng * GSTR + k];
            const float4 w0 = *(const float4*)(Wp + k * 64 + cm0);
            const float4 w1 = *(const float4*)(Wp + k * 64 + cm0 + 4);
            a1[0] += hv * w0.x; a1[1] += hv * w0.y;
            a1[2] += hv * w0.z; a1[3] += hv * w0.w;
            a1[4] += hv * w1.x; a1[5] += hv * w1.y;
            a1[6] += hv * w1.z; a1[7] += hv * w1.w;
        }
        *(float4*)(gS + ng * GSTR + 64 + cm0) =
            make_float4(elu_f(a1[0]), elu_f(a1[1]), elu_f(a1[2]), elu_f(a1[3]));
        *(float4*)(gS + ng * GSTR + 64 + cm0 + 4) =
            make_float4(elu_f(a1[4]), elu_f(a1[5]), elu_f(a1[6]), elu_f(a1[7]));
    }
    __syncthreads();
    *(float4*)(Wp + t * 4) = *(const float4*)(Wm2 + t * 4);
    __syncthreads();
    // MLP2: 32 nodes x 32 cols, thread (t<256) = 1 node x 4 cols
    if (t < 256) {
        const int nn = t >> 3;            // 0..31
        const int cc0 = (t & 7) * 4;
        float a2[4];
#pragma unroll
        for (int u = 0; u < 4; ++u) a2[u] = vN[64 + cc0 + u];
#pragma unroll 4
        for (int j = 0; j < 64; ++j) {
            const float ov = gS[nn * GSTR + 64 + j];
            const float4 w = *(const float4*)(Wp + j * 32 + cc0);
            a2[0] += ov * w.x; a2[1] += ov * w.y;
            a2[2] += ov * w.z; a2[3] += ov * w.w;
        }
        __syncthreads();
        *(float4*)(gS + nn * GSTR + cc0) =
            make_float4(elu_f(a2[0]), elu_f(a2[1]), elu_f(a2[2]), elu_f(a2[3]));
    } else {
        __syncthreads();
    }
    __syncthreads();
    // MLP3: 32 nodes x 8 cols, thread (t<256) = 1 output
    if (t < 256) {
        const int nl = t >> 3;
        const int c3 = t & 7;
        const int n = n0 + nl;
        if (n < n_nodes) {
            float a3 = vN[96 + c3];
#pragma unroll 4
            for (int j = 0; j < 32; ++j)
                a3 += gS[nl * GSTR + j] * vN[104 + j * 8 + c3];
            mlp_out[(size_t)n * 8 + c3] = a3;
        }
    }
}

// ---------------------------------------------------------------------------
extern "C" void kernel_launch(void* const* d_in, const int* in_sizes, int n_in,
                              void* d_out, int out_size, void* d_ws, size_t ws_size,
                              hipStream_t stream) {
    const float* x     = (const float*)d_in[0];
    const int*   ei    = (const int*)d_in[1];
    const float* Wenc1 = (const float*)d_in[2];
    const float* benc1 = (const float*)d_in[3];
    const float* Wenc2 = (const float*)d_in[4];
    const float* benc2 = (const float*)d_in[5];
    const float* Wg[3]  = {(const float*)d_in[6],  (const float*)d_in[10], (const float*)d_in[14]};
    const float* as_[3] = {(const float*)d_in[7],  (const float*)d_in[11], (const float*)d_in[15]};
    const float* ad_[3] = {(const float*)d_in[8],  (const float*)d_in[12], (const float*)d_in[16]};
    const float* bg[3]  = {(const float*)d_in[9],  (const float*)d_in[13], (const float*)d_in[17]};
    const float* Wo1 = (const float*)d_in[18];
    const float* bo1 = (const float*)d_in[19];
    const float* Wo2 = (const float*)d_in[20];
    const float* bo2 = (const float*)d_in[21];
    const float* Wo3 = (const float*)d_in[22];
    const float* bo3 = (const float*)d_in[23];

    const int N = in_sizes[0] / 8;
    const int E = in_sizes[1] / 2;
    const int Etot = E + N;
    const int nblk = (N + SCAN_B - 1) / SCAN_B;  // 79
    const int FB = (Etot + 255) / 256;
    const int NB64 = (N + 63) / 64;
    const int NB32 = (N + 31) / 32;

    float* buf0  = (float*)d_ws;                  // N*64
    float* buf1  = buf0 + (size_t)N * 64;         // N*64
    float* asA   = buf1 + (size_t)N * 64;         // N*4
    float* adA   = asA + (size_t)N * 4;           // N*4
    float* asB   = adA + (size_t)N * 4;           // N*4
    float* adB   = asB + (size_t)N * 4;           // N*4
    float* vfold = adB + (size_t)N * 4;           // 3*512
    int* rowptr = (int*)(vfold + 3 * 512);        // N+1 (+pad)
    int* cursor = rowptr + (N + 2);               // N
    int* cnt    = cursor + N;                     // N
    int* ready  = cnt + N;                        // 128
    int* flag   = ready + 128;                    // 1 (+pad)
    int* col    = flag + 2;                       // Etot

    prep_kernel<<<nblk + 6, 256, 0, stream>>>(ei,
        Wg[0], as_[0], ad_[0], Wg[1], as_[1], ad_[1], Wg[2], as_[2], ad_[2],
        cnt, ready, flag, vfold, N);
    count_kernel<<<(Etot + 255) / 256, 256, 0, stream>>>(ei, flag, E, Etot, cnt);
    scan_onepass_kernel<<<nblk, SCAN_B, 0, stream>>>(cnt, ready, rowptr, cursor, N);
    fillenc_kernel<<<FB + NB64, 256, 0, stream>>>(ei, flag, E, Etot, cursor, col, FB,
                                                  x, Wenc1, benc1, Wenc2, benc2,
                                                  vfold, buf0, asA, adA, N);

    // layer 0: read dots A, write dots B
    gat_fused_kernel<<<NB32, 512, 0, stream>>>(
        buf0, asA, adA, rowptr, col, Wg[0], bg[0], vfold + 512, 1,
        buf1, asB, adB, Wo1, bo1, Wo2, bo2, Wo3, bo3, (float*)d_out, N);
    // layer 1: read dots B, write dots A
    gat_fused_kernel<<<NB32, 512, 0, stream>>>(
        buf1, asB, adB, rowptr, col, Wg[1], bg[1], vfold + 1024, 1,
        buf0, asA, adA, Wo1, bo1, Wo2, bo2, Wo3, bo3, (float*)d_out, N);
    // layer 2: read dots A, fused output MLP -> d_out
    gat_fused_kernel<<<NB32, 512, 0, stream>>>(
        buf0, asA, adA, rowptr, col, Wg[2], bg[2], vfold, 0,
        buf1, asB, adB, Wo1, bo1, Wo2, bo2, Wo3, bo3, (float*)d_out, N);
}

// Round 13
// 309.589 us; speedup vs baseline: 1.0560x; 1.0474x over previous
//
#include <hip/hip_runtime.h>
#include <cstdint>
#include <cstddef>

#define NEG_SLOPE 0.2f

__device__ __forceinline__ float elu_f(float x) {
    return x > 0.f ? x : expm1f(x);
}

// ---------------------------------------------------------------------------
// P0: zero cnt + ready + done-flags, detect edge-index layout, folded
// attention vectors for all 3 layers. Blocks 0..78 zero; 79..84 fold.
// vfold[l][k*8+j] = sum_cc W_l[k, h*64+cc]*att[h,cc] (j<4 src, j>=4 dst, h=j&3)
// ---------------------------------------------------------------------------
__global__ __launch_bounds__(256) void prep_kernel(
    const int* __restrict__ ei,
    const float* __restrict__ W0, const float* __restrict__ as0, const float* __restrict__ ad0,
    const float* __restrict__ W1, const float* __restrict__ as1, const float* __restrict__ ad1,
    const float* __restrict__ W2, const float* __restrict__ as2, const float* __restrict__ ad2,
    int* __restrict__ cnt, int* __restrict__ ready, int* __restrict__ flag,
    int* __restrict__ dones, float* __restrict__ vfold, int n) {
    const int b = blockIdx.x, t = threadIdx.x;
    if (b < 79) {
        const int i = b * 256 + t;
        if (i < n) cnt[i] = 0;
        if (b == 0) {
            if (t < 128) ready[t] = 0;
            if (t == 0) {
                int acc = 0;
#pragma unroll
                for (int k = 0; k < 8; ++k) acc |= ei[2 * k + 1];
                flag[0] = (acc == 0) ? 1 : 0;
                dones[0] = 0;   // count_done
                dones[1] = 0;   // scan_done
            }
        }
        return;
    }
    const int e = (b - 79) * 256 + t;
    if (e >= 1536) return;
    const int l = e >> 9, rem = e & 511;
    const int k = rem >> 3, j = rem & 7, h = j & 3;
    const float* W   = (l == 0) ? W0  : (l == 1) ? W1  : W2;
    const float* as_ = (l == 0) ? as0 : (l == 1) ? as1 : as2;
    const float* ad_ = (l == 0) ? ad0 : (l == 1) ? ad1 : ad2;
    const float* av = (j < 4) ? as_ : ad_;
    const float* wr = W + k * 256 + h * 64;
    const float* ar = av + h * 64;
    float s = 0.f;
#pragma unroll 8
    for (int cc = 0; cc < 64; ++cc) s += wr[cc] * ar[cc];
    vfold[l * 512 + k * 8 + j] = s;
}

#define SCAN_B 256

// ---------------------------------------------------------------------------
// build_kernel: one dispatch for {encoder || count} -> scan -> fill.
// Roles by blockIdx.x: [0,NB) encoder (independent of CSR; then joins fill),
// [NB,NB+CB) count (atomic degree histogram; signals dones[0]),
// [NB+CB,NB+CB+SB) scan (waits dones[0]==CB; one-pass lookback scan;
// signals dones[1]; joins fill). Fill = grid-stride CSR scatter by the
// NB+SB filler blocks after dones[1]==SB.
// Deadlock-safety: max concurrent spinners = NB+SB = 392 blocks; capacity
// >= 4 blocks/CU x 256 CU = 1024 co-resident, so count workers always have
// slots regardless of dispatch order. cnt is read via atomicAdd(p,0)
// (L2-coherent); __threadfence before each done-signal.
// ---------------------------------------------------------------------------
#define H1STR 68
__global__ __launch_bounds__(256, 4) void build_kernel(
    const int* __restrict__ ei, const int* __restrict__ flag,
    int E, int Etot, int NB, int CB, int SB,
    int* __restrict__ cnt, int* __restrict__ ready, int* __restrict__ dones,
    int* __restrict__ rowptr, int* __restrict__ cursor, int* __restrict__ col,
    const float* __restrict__ x,
    const float* __restrict__ W1, const float* __restrict__ b1,
    const float* __restrict__ W2, const float* __restrict__ b2,
    const float* __restrict__ vfold0,
    float* __restrict__ h0, float* __restrict__ asrc, float* __restrict__ adst,
    int n_nodes) {
    __shared__ float W1s[256];
    __shared__ float b1s[32];
    __shared__ float W2s[2048];
    __shared__ float b2s[64];
    __shared__ float vsd[512];
    __shared__ float xS[512];
    __shared__ float h1T[32 * H1STR];
    __shared__ int scb[SCAN_B];
    __shared__ int sred[128];
    __shared__ int s_pref;
    const int b = blockIdx.x, t = threadIdx.x;

    // ================= count role =================
    if (b >= NB && b < NB + CB) {
        const int e = (b - NB) * 256 + t;
        if (e < Etot) {
            int d;
            if (e < E) d = flag[0] ? ei[2 * (size_t)(E + e)] : ei[E + e];
            else       d = e - E;  // self loop
            atomicAdd(&cnt[d], 1);
        }
        __syncthreads();
        if (t == 0) { __threadfence(); atomicAdd(&dones[0], 1); }
        return;
    }

    int rank;
    if (b >= NB + CB) {
        // ================= scan role =================
        const int sb = b - NB - CB;
        if (t == 0) {
            while (atomicAdd(&dones[0], 0) < CB) __builtin_amdgcn_s_sleep(2);
        }
        __syncthreads();
        const int g = sb * SCAN_B + t;
        const int v = (g < n_nodes) ? atomicAdd(&cnt[g], 0) : 0;
        scb[t] = v;
        __syncthreads();
        for (int off = 1; off < SCAN_B; off <<= 1) {
            int add = (t >= off) ? scb[t - off] : 0;
            __syncthreads();
            scb[t] += add;
            __syncthreads();
        }
        if (t == SCAN_B - 1) atomicExch(&ready[sb], scb[SCAN_B - 1] + 1);
        if (t < 128) {
            int pv = 0;
            if (t < sb) {
                do { pv = atomicAdd(&ready[t], 0); __builtin_amdgcn_s_sleep(1); } while (pv == 0);
                pv -= 1;
            }
            sred[t] = pv;
        }
        __syncthreads();
        if (t == 0) {
            int s = 0;
#pragma unroll 8
            for (int i = 0; i < 128; ++i) s += sred[i];
            s_pref = s;
        }
        __syncthreads();
        const int pre = s_pref;
        if (g < n_nodes) {
            const int e = pre + scb[t];
            rowptr[g + 1] = e;
            cursor[g] = e - v;
            if (g == 0) rowptr[0] = 0;
        }
        __syncthreads();
        if (t == 0) { __threadfence(); atomicAdd(&dones[1], 1); }
        rank = NB + sb;
    } else {
        // ================= encoder role =================
        const int n0 = b * 64;
        const int rem = n_nodes - n0;

        *(float4*)(W2s + t * 4) = *(const float4*)(W2 + t * 4);
        *(float4*)(W2s + 1024 + t * 4) = *(const float4*)(W2 + 1024 + t * 4);
        if (t < 64)  *(float4*)(W1s + t * 4) = *(const float4*)(W1 + t * 4);
        if (t < 8)   *(float4*)(b1s + t * 4) = *(const float4*)(b1 + t * 4);
        if (t < 16)  *(float4*)(b2s + t * 4) = *(const float4*)(b2 + t * 4);
        if (t < 128) *(float4*)(vsd + t * 4) = *(const float4*)(vfold0 + t * 4);
        if (t < 128) {
            const int fidx = t * 4;
            float4 v = make_float4(0.f, 0.f, 0.f, 0.f);
            if (fidx < rem * 8) v = *(const float4*)(x + (size_t)n0 * 8 + fidx);
            *(float4*)(xS + fidx) = v;
        }
        __syncthreads();

        {
            const int nl = t >> 2;
            const int j0 = (t & 3) * 8;
            const float4 xa = *(const float4*)(xS + nl * 8);
            const float4 xb = *(const float4*)(xS + nl * 8 + 4);
            const float xk[8] = {xa.x, xa.y, xa.z, xa.w, xb.x, xb.y, xb.z, xb.w};
            float a[8];
#pragma unroll
            for (int u = 0; u < 8; ++u) a[u] = b1s[j0 + u];
#pragma unroll
            for (int k = 0; k < 8; ++k) {
                const float4 w0 = *(const float4*)(W1s + k * 32 + j0);
                const float4 w1 = *(const float4*)(W1s + k * 32 + j0 + 4);
                a[0] += xk[k] * w0.x; a[1] += xk[k] * w0.y;
                a[2] += xk[k] * w0.z; a[3] += xk[k] * w0.w;
                a[4] += xk[k] * w1.x; a[5] += xk[k] * w1.y;
                a[6] += xk[k] * w1.z; a[7] += xk[k] * w1.w;
            }
#pragma unroll
            for (int u = 0; u < 8; ++u) h1T[(j0 + u) * H1STR + nl] = elu_f(a[u]);
        }
        __syncthreads();

        const int cg = t & 15;
        const int nq = t >> 4;
        const int c0 = cg * 4;
        float acc[4][4];
#pragma unroll
        for (int i = 0; i < 4; ++i)
#pragma unroll
            for (int c = 0; c < 4; ++c) acc[i][c] = b2s[c0 + c];
#pragma unroll 8
        for (int k = 0; k < 32; ++k) {
            const float4 hv = *(const float4*)(h1T + k * H1STR + nq * 4);
            const float4 wv = *(const float4*)(W2s + k * 64 + c0);
            const float hvv[4] = {hv.x, hv.y, hv.z, hv.w};
#pragma unroll
            for (int i = 0; i < 4; ++i) {
                acc[i][0] += hvv[i] * wv.x; acc[i][1] += hvv[i] * wv.y;
                acc[i][2] += hvv[i] * wv.z; acc[i][3] += hvv[i] * wv.w;
            }
        }
        float o[4][4];
#pragma unroll
        for (int i = 0; i < 4; ++i)
#pragma unroll
            for (int c = 0; c < 4; ++c) o[i][c] = elu_f(acc[i][c]);

#pragma unroll
        for (int i = 0; i < 4; ++i) {
            const int n = n0 + nq * 4 + i;
            if (n < n_nodes)
                *(float4*)(h0 + (size_t)n * 64 + c0) =
                    make_float4(o[i][0], o[i][1], o[i][2], o[i][3]);
        }
        float ad[4][8];
#pragma unroll
        for (int i = 0; i < 4; ++i)
#pragma unroll
            for (int jj = 0; jj < 8; ++jj) ad[i][jj] = 0.f;
#pragma unroll
        for (int c = 0; c < 4; ++c) {
            const float4 v0 = *(const float4*)(vsd + (c0 + c) * 8);
            const float4 v1 = *(const float4*)(vsd + (c0 + c) * 8 + 4);
#pragma unroll
            for (int i = 0; i < 4; ++i) {
                ad[i][0] += o[i][c] * v0.x; ad[i][1] += o[i][c] * v0.y;
                ad[i][2] += o[i][c] * v0.z; ad[i][3] += o[i][c] * v0.w;
                ad[i][4] += o[i][c] * v1.x; ad[i][5] += o[i][c] * v1.y;
                ad[i][6] += o[i][c] * v1.z; ad[i][7] += o[i][c] * v1.w;
            }
        }
#pragma unroll
        for (int off = 1; off < 16; off <<= 1) {
#pragma unroll
            for (int i = 0; i < 4; ++i)
#pragma unroll
                for (int jj = 0; jj < 8; ++jj)
                    ad[i][jj] += __shfl_xor(ad[i][jj], off);
        }
        if (cg == 0) {
#pragma unroll
            for (int i = 0; i < 4; ++i) {
                const int n = n0 + nq * 4 + i;
                if (n < n_nodes) {
#pragma unroll
                    for (int h = 0; h < 4; ++h) {
                        asrc[n * 4 + h] = ad[i][h];
                        adst[n * 4 + h] = ad[i][4 + h];
                    }
                }
            }
        }
        rank = b;
    }

    // ================= fill (encoder + scan blocks) =================
    if (t == 0) {
        while (atomicAdd(&dones[1], 0) < SB) __builtin_amdgcn_s_sleep(2);
    }
    __syncthreads();
    {
        const int fl = flag[0];
        const int F = NB + SB;
        for (int e = rank * 256 + t; e < Etot; e += F * 256) {
            int s, d;
            if (e < E) {
                if (fl) { s = ei[2 * (size_t)e]; d = ei[2 * (size_t)(E + e)]; }
                else    { s = ei[e];             d = ei[E + e]; }
            } else {
                s = d = e - E;
            }
            int pos = atomicAdd(&cursor[d], 1);
            col[pos] = s;
        }
    }
}

// ---------------------------------------------------------------------------
// Fused GAT layer — EXACT R2 form (best measured: 48.7 us/layer, 281.8 total).
// 32 nodes/block, 625 blocks, 512 threads, 1 node per 16-lane agg group,
// 4 blocks/CU. GEMM on t<256: 2 nodes x 4 cols x 4-k, b128 both operands.
// (R12's t<128 reblock reverted: it halved active GEMM waves and regressed
// 48.7 -> 64.3 us — the phase is latency/overlap-bound, not DS-issue-bound.)
// ---------------------------------------------------------------------------
#define GSTR 132
__global__ __launch_bounds__(512, 8) void gat_fused_kernel(
    const float* __restrict__ bin, const float* __restrict__ asrc,
    const float* __restrict__ adst, const int* __restrict__ rowptr,
    const int* __restrict__ col,
    const float* __restrict__ W, const float* __restrict__ bias,
    const float* __restrict__ vfold_next, int has_next,
    float* __restrict__ out,
    float* __restrict__ nasrc, float* __restrict__ nadst,
    const float* __restrict__ Wm1, const float* __restrict__ bm1,
    const float* __restrict__ Wm2, const float* __restrict__ bm2,
    const float* __restrict__ Wm3, const float* __restrict__ bm3,
    float* __restrict__ mlp_out, int n_nodes) {
    __shared__ float gS[32 * GSTR];   // 16,896 B
    __shared__ float Wp[4096];        // 16,384 B
    __shared__ float vN[512];         //  2,048 B
    const int t = threadIdx.x;
    const int n0 = blockIdx.x * 32;
    const int grp = t >> 4;           // 0..31 : ONE node per group (agg)
    const int q = t & 15;             // lane in group
    const int c0 = q * 4;

    if (has_next && t < 128) *(float4*)(vN + t * 4) = *(const float4*)(vfold_next + t * 4);

    // ============ phase 1: aggregation (1 node per 16-lane group) ============
    float keep[8];                    // normalized heads {2,3}
    {
        const int n = n0 + grp;
        float acc[4][4];
#pragma unroll
        for (int h = 0; h < 4; ++h)
#pragma unroll
            for (int z = 0; z < 4; ++z) acc[h][z] = 0.f;
        if (n < n_nodes) {
            float4 den4 = make_float4(0.f, 0.f, 0.f, 0.f);
            const float4 ad4 = *(const float4*)(adst + (size_t)n * 4);
            const int start = rowptr[n], end = rowptr[n + 1];
            for (int base = start; base < end; base += 16) {
                const int cnt = min(16, end - base);
                int c = 0;
                float4 w4 = make_float4(0.f, 0.f, 0.f, 0.f);
                if (base + q < end) {
                    c = col[base + q];
                    const float4 av = *(const float4*)(asrc + (size_t)c * 4);
                    float l0 = av.x + ad4.x; l0 = l0 > 0.f ? l0 : NEG_SLOPE * l0;
                    float l1 = av.y + ad4.y; l1 = l1 > 0.f ? l1 : NEG_SLOPE * l1;
                    float l2 = av.z + ad4.z; l2 = l2 > 0.f ? l2 : NEG_SLOPE * l2;
                    float l3 = av.w + ad4.w; l3 = l3 > 0.f ? l3 : NEG_SLOPE * l3;
                    w4.x = __expf(fminf(l0, 60.f));
                    w4.y = __expf(fminf(l1, 60.f));
                    w4.z = __expf(fminf(l2, 60.f));
                    w4.w = __expf(fminf(l3, 60.f));
                    den4.x += w4.x; den4.y += w4.y; den4.z += w4.z; den4.w += w4.w;
                }
                int j = 0;
                for (; j + 4 <= cnt; j += 4) {
#pragma unroll
                    for (int u = 0; u < 4; ++u) {
                        const int s = __shfl(c, j + u, 16);
                        const float4 hv = *(const float4*)(bin + (size_t)s * 64 + q * 4);
                        const float wx = __shfl(w4.x, j + u, 16);
                        const float wy = __shfl(w4.y, j + u, 16);
                        const float wz = __shfl(w4.z, j + u, 16);
                        const float ww = __shfl(w4.w, j + u, 16);
                        acc[0][0] += wx * hv.x; acc[0][1] += wx * hv.y;
                        acc[0][2] += wx * hv.z; acc[0][3] += wx * hv.w;
                        acc[1][0] += wy * hv.x; acc[1][1] += wy * hv.y;
                        acc[1][2] += wy * hv.z; acc[1][3] += wy * hv.w;
                        acc[2][0] += wz * hv.x; acc[2][1] += wz * hv.y;
                        acc[2][2] += wz * hv.z; acc[2][3] += wz * hv.w;
                        acc[3][0] += ww * hv.x; acc[3][1] += ww * hv.y;
                        acc[3][2] += ww * hv.z; acc[3][3] += ww * hv.w;
                    }
                }
                for (; j < cnt; ++j) {
                    const int s = __shfl(c, j, 16);
                    const float4 hv = *(const float4*)(bin + (size_t)s * 64 + q * 4);
                    const float wx = __shfl(w4.x, j, 16);
                    const float wy = __shfl(w4.y, j, 16);
                    const float wz = __shfl(w4.z, j, 16);
                    const float ww = __shfl(w4.w, j, 16);
                    acc[0][0] += wx * hv.x; acc[0][1] += wx * hv.y;
                    acc[0][2] += wx * hv.z; acc[0][3] += wx * hv.w;
                    acc[1][0] += wy * hv.x; acc[1][1] += wy * hv.y;
                    acc[1][2] += wy * hv.z; acc[1][3] += wy * hv.w;
                    acc[2][0] += wz * hv.x; acc[2][1] += wz * hv.y;
                    acc[2][2] += wz * hv.z; acc[2][3] += wz * hv.w;
                    acc[3][0] += ww * hv.x; acc[3][1] += ww * hv.y;
                    acc[3][2] += ww * hv.z; acc[3][3] += ww * hv.w;
                }
            }
#pragma unroll
            for (int off = 1; off < 16; off <<= 1) {
                den4.x += __shfl_xor(den4.x, off, 16);
                den4.y += __shfl_xor(den4.y, off, 16);
                den4.z += __shfl_xor(den4.z, off, 16);
                den4.w += __shfl_xor(den4.w, off, 16);
            }
            const float i0 = 1.f / (den4.x + 1e-16f);
            const float i1 = 1.f / (den4.y + 1e-16f);
            const float i2 = 1.f / (den4.z + 1e-16f);
            const float i3 = 1.f / (den4.w + 1e-16f);
            *(float4*)(gS + grp * GSTR + c0) =
                make_float4(acc[0][0] * i0, acc[0][1] * i0, acc[0][2] * i0, acc[0][3] * i0);
            *(float4*)(gS + grp * GSTR + 64 + c0) =
                make_float4(acc[1][0] * i1, acc[1][1] * i1, acc[1][2] * i1, acc[1][3] * i1);
            keep[0] = acc[2][0] * i2; keep[1] = acc[2][1] * i2;
            keep[2] = acc[2][2] * i2; keep[3] = acc[2][3] * i2;
            keep[4] = acc[3][0] * i3; keep[5] = acc[3][1] * i3;
            keep[6] = acc[3][2] * i3; keep[7] = acc[3][3] * i3;
        } else {
            const float4 z4 = make_float4(0.f, 0.f, 0.f, 0.f);
            *(float4*)(gS + grp * GSTR + c0) = z4;
            *(float4*)(gS + grp * GSTR + 64 + c0) = z4;
#pragma unroll
            for (int u = 0; u < 8; ++u) keep[u] = 0.f;
        }
    }

    // ============ phase 2: head-mean projection GEMM (t<256, 2 nodes) =======
    const int ng2 = t >> 4;           // valid when t<256
    float ga2[2][4];
#pragma unroll
    for (int i = 0; i < 2; ++i)
#pragma unroll
        for (int c = 0; c < 4; ++c) ga2[i][c] = 0.f;

#pragma unroll
    for (int half = 0; half < 2; ++half) {
        if (half == 1) {
            // last half-0 barrier passed: swap heads {2,3} into gS
            *(float4*)(gS + grp * GSTR + c0) =
                make_float4(keep[0], keep[1], keep[2], keep[3]);
            *(float4*)(gS + grp * GSTR + 64 + c0) =
                make_float4(keep[4], keep[5], keep[6], keep[7]);
        }
#pragma unroll
        for (int s = 0; s < 2; ++s) {
#pragma unroll
            for (int j = 0; j < 2; ++j) {
                const int f4 = j * 512 + t;
                const int kl = f4 >> 4;
                const int c = (f4 & 15) * 4;
                const int m = half * 128 + s * 64 + kl;
                const int h = m >> 6, kk = m & 63;
                *(float4*)(Wp + kl * 64 + c) = *(const float4*)(W + kk * 256 + h * 64 + c);
            }
            __syncthreads();
            if (t < 256) {
#pragma unroll 4
                for (int ks = 0; ks < 64; ks += 4) {
                    const float4 a0 = *(const float4*)(gS + (ng2 * 2 + 0) * GSTR + s * 64 + ks);
                    const float4 a1 = *(const float4*)(gS + (ng2 * 2 + 1) * GSTR + s * 64 + ks);
                    const float4 w0 = *(const float4*)(Wp + (ks + 0) * 64 + c0);
                    const float4 w1 = *(const float4*)(Wp + (ks + 1) * 64 + c0);
                    const float4 w2 = *(const float4*)(Wp + (ks + 2) * 64 + c0);
                    const float4 w3 = *(const float4*)(Wp + (ks + 3) * 64 + c0);
                    ga2[0][0] += a0.x * w0.x + a0.y * w1.x + a0.z * w2.x + a0.w * w3.x;
                    ga2[0][1] += a0.x * w0.y + a0.y * w1.y + a0.z * w2.y + a0.w * w3.y;
                    ga2[0][2] += a0.x * w0.z + a0.y * w1.z + a0.z * w2.z + a0.w * w3.z;
                    ga2[0][3] += a0.x * w0.w + a0.y * w1.w + a0.z * w2.w + a0.w * w3.w;
                    ga2[1][0] += a1.x * w0.x + a1.y * w1.x + a1.z * w2.x + a1.w * w3.x;
                    ga2[1][1] += a1.x * w0.y + a1.y * w1.y + a1.z * w2.y + a1.w * w3.y;
                    ga2[1][2] += a1.x * w0.z + a1.y * w1.z + a1.z * w2.z + a1.w * w3.z;
                    ga2[1][3] += a1.x * w0.w + a1.y * w1.w + a1.z * w2.w + a1.w * w3.w;
                }
            }
            __syncthreads();
        }
    }

    // ============ epilogue: bias + head-mean + residual (t<256) ============
    float o[2][4];
    if (t < 256) {
        const float4 bb = *(const float4*)(bias + c0);
#pragma unroll
        for (int i = 0; i < 2; ++i) {
            const int n = n0 + ng2 * 2 + i;
            if (n < n_nodes) {
                const float4 x4 = *(const float4*)(bin + (size_t)n * 64 + c0);
                o[i][0] = 0.25f * ga2[i][0] + bb.x + x4.x;
                o[i][1] = 0.25f * ga2[i][1] + bb.y + x4.y;
                o[i][2] = 0.25f * ga2[i][2] + bb.z + x4.z;
                o[i][3] = 0.25f * ga2[i][3] + bb.w + x4.w;
                if (has_next)
                    *(float4*)(out + (size_t)n * 64 + c0) =
                        make_float4(o[i][0], o[i][1], o[i][2], o[i][3]);
            } else {
                o[i][0] = o[i][1] = o[i][2] = o[i][3] = 0.f;
            }
        }
    } else {
#pragma unroll
        for (int i = 0; i < 2; ++i)
            o[i][0] = o[i][1] = o[i][2] = o[i][3] = 0.f;
    }

    if (has_next) {
        if (t < 256) {
            float pj[2][8];
#pragma unroll
            for (int i = 0; i < 2; ++i)
#pragma unroll
                for (int jj = 0; jj < 8; ++jj) pj[i][jj] = 0.f;
#pragma unroll
            for (int c = 0; c < 4; ++c) {
                const float4 v0 = *(const float4*)(vN + (c0 + c) * 8);
                const float4 v1 = *(const float4*)(vN + (c0 + c) * 8 + 4);
#pragma unroll
                for (int i = 0; i < 2; ++i) {
                    pj[i][0] += o[i][c] * v0.x; pj[i][1] += o[i][c] * v0.y;
                    pj[i][2] += o[i][c] * v0.z; pj[i][3] += o[i][c] * v0.w;
                    pj[i][4] += o[i][c] * v1.x; pj[i][5] += o[i][c] * v1.y;
                    pj[i][6] += o[i][c] * v1.z; pj[i][7] += o[i][c] * v1.w;
                }
            }
#pragma unroll
            for (int off = 1; off < 16; off <<= 1) {
#pragma unroll
                for (int i = 0; i < 2; ++i)
#pragma unroll
                    for (int jj = 0; jj < 8; ++jj)
                        pj[i][jj] += __shfl_xor(pj[i][jj], off);
            }
            if (q == 0) {
#pragma unroll
                for (int i = 0; i < 2; ++i) {
                    const int n = n0 + ng2 * 2 + i;
                    if (n < n_nodes) {
#pragma unroll
                        for (int h = 0; h < 4; ++h) {
                            nasrc[n * 4 + h] = pj[i][h];
                            nadst[n * 4 + h] = pj[i][4 + h];
                        }
                    }
                }
            }
        }
        return;
    }

    // ============ fused output MLP 64->64->32->8 (last layer, 32 nodes) =====
    if (t < 256) {
#pragma unroll
        for (int i = 0; i < 2; ++i)
            *(float4*)(gS + (ng2 * 2 + i) * GSTR + c0) =
                make_float4(o[i][0], o[i][1], o[i][2], o[i][3]);
    }
#pragma unroll
    for (int j = 0; j < 2; ++j)
        *(float4*)(Wp + (j * 512 + t) * 4) = *(const float4*)(Wm1 + (j * 512 + t) * 4);
    if (t < 64) vN[t] = bm1[t];
    else if (t < 96) vN[t] = bm2[t - 64];
    else if (t < 104) vN[t] = bm3[t - 96];
    if (t < 256) vN[104 + t] = Wm3[t];
    __syncthreads();
    // MLP1: 32 nodes x 64 cols, thread (t<256) = 1 node x 8 cols
    if (t < 256) {
        const int ng = t >> 3;            // 0..31
        const int cm0 = (t & 7) * 8;
        float a1[8];
#pragma unroll
        for (int u = 0; u < 8; ++u) a1[u] = vN[cm0 + u];
#pragma unroll 4
        for (int k = 0; k < 64; ++k) {
            const float hv = gS[ng * GSTR + k];
            const float4 w0 = *(const float4*)(Wp + k * 64 + cm0);
            const float4 w1 = *(const float4*)(Wp + k * 64 + cm0 + 4);
            a1[0] += hv * w0.x; a1[1] += hv * w0.y;
            a1[2] += hv * w0.z; a1[3] += hv * w0.w;
            a1[4] += hv * w1.x; a1[5] += hv * w1.y;
            a1[6] += hv * w1.z; a1[7] += hv * w1.w;
        }
        *(float4*)(gS + ng * GSTR + 64 + cm0) =
            make_float4(elu_f(a1[0]), elu_f(a1[1]), elu_f(a1[2]), elu_f(a1[3]));
        *(float4*)(gS + ng * GSTR + 64 + cm0 + 4) =
            make_float4(elu_f(a1[4]), elu_f(a1[5]), elu_f(a1[6]), elu_f(a1[7]));
    }
    __syncthreads();
    *(float4*)(Wp + t * 4) = *(const float4*)(Wm2 + t * 4);
    __syncthreads();
    // MLP2: 32 nodes x 32 cols, thread (t<256) = 1 node x 4 cols
    if (t < 256) {
        const int nn = t >> 3;            // 0..31
        const int cc0 = (t & 7) * 4;
        float a2[4];
#pragma unroll
        for (int u = 0; u < 4; ++u) a2[u] = vN[64 + cc0 + u];
#pragma unroll 4
        for (int j = 0; j < 64; ++j) {
            const float ov = gS[nn * GSTR + 64 + j];
            const float4 w = *(const float4*)(Wp + j * 32 + cc0);
            a2[0] += ov * w.x; a2[1] += ov * w.y;
            a2[2] += ov * w.z; a2[3] += ov * w.w;
        }
        __syncthreads();
        *(float4*)(gS + nn * GSTR + cc0) =
            make_float4(elu_f(a2[0]), elu_f(a2[1]), elu_f(a2[2]), elu_f(a2[3]));
    } else {
        __syncthreads();
    }
    __syncthreads();
    // MLP3: 32 nodes x 8 cols, thread (t<256) = 1 output
    if (t < 256) {
        const int nl = t >> 3;
        const int c3 = t & 7;
        const int n = n0 + nl;
        if (n < n_nodes) {
            float a3 = vN[96 + c3];
#pragma unroll 4
            for (int j = 0; j < 32; ++j)
                a3 += gS[nl * GSTR + j] * vN[104 + j * 8 + c3];
            mlp_out[(size_t)n * 8 + c3] = a3;
        }
    }
}

// ---------------------------------------------------------------------------
extern "C" void kernel_launch(void* const* d_in, const int* in_sizes, int n_in,
                              void* d_out, int out_size, void* d_ws, size_t ws_size,
                              hipStream_t stream) {
    const float* x     = (const float*)d_in[0];
    const int*   ei    = (const int*)d_in[1];
    const float* Wenc1 = (const float*)d_in[2];
    const float* benc1 = (const float*)d_in[3];
    const float* Wenc2 = (const float*)d_in[4];
    const float* benc2 = (const float*)d_in[5];
    const float* Wg[3]  = {(const float*)d_in[6],  (const float*)d_in[10], (const float*)d_in[14]};
    const float* as_[3] = {(const float*)d_in[7],  (const float*)d_in[11], (const float*)d_in[15]};
    const float* ad_[3] = {(const float*)d_in[8],  (const float*)d_in[12], (const float*)d_in[16]};
    const float* bg[3]  = {(const float*)d_in[9],  (const float*)d_in[13], (const float*)d_in[17]};
    const float* Wo1 = (const float*)d_in[18];
    const float* bo1 = (const float*)d_in[19];
    const float* Wo2 = (const float*)d_in[20];
    const float* bo2 = (const float*)d_in[21];
    const float* Wo3 = (const float*)d_in[22];
    const float* bo3 = (const float*)d_in[23];

    const int N = in_sizes[0] / 8;
    const int E = in_sizes[1] / 2;
    const int Etot = E + N;
    const int nblk = (N + SCAN_B - 1) / SCAN_B;  // 79 (scan blocks, SB)
    const int CB = (Etot + 255) / 256;           // count blocks
    const int NB64 = (N + 63) / 64;              // encoder blocks
    const int NB32 = (N + 31) / 32;

    float* buf0  = (float*)d_ws;                  // N*64
    float* buf1  = buf0 + (size_t)N * 64;         // N*64
    float* asA   = buf1 + (size_t)N * 64;         // N*4
    float* adA   = asA + (size_t)N * 4;           // N*4
    float* asB   = adA + (size_t)N * 4;           // N*4
    float* adB   = asB + (size_t)N * 4;           // N*4
    float* vfold = adB + (size_t)N * 4;           // 3*512
    int* rowptr = (int*)(vfold + 3 * 512);        // N+1 (+pad)
    int* cursor = rowptr + (N + 2);               // N
    int* cnt    = cursor + N;                     // N
    int* ready  = cnt + N;                        // 128
    int* flag   = ready + 128;                    // 2
    int* dones  = flag + 2;                       // 2 (count_done, scan_done)
    int* col    = dones + 2;                      // Etot

    prep_kernel<<<nblk + 6, 256, 0, stream>>>(ei,
        Wg[0], as_[0], ad_[0], Wg[1], as_[1], ad_[1], Wg[2], as_[2], ad_[2],
        cnt, ready, flag, dones, vfold, N);

    build_kernel<<<NB64 + CB + nblk, 256, 0, stream>>>(
        ei, flag, E, Etot, NB64, CB, nblk,
        cnt, ready, dones, rowptr, cursor, col,
        x, Wenc1, benc1, Wenc2, benc2, vfold, buf0, asA, adA, N);

    // layer 0: read dots A, write dots B
    gat_fused_kernel<<<NB32, 512, 0, stream>>>(
        buf0, asA, adA, rowptr, col, Wg[0], bg[0], vfold + 512, 1,
        buf1, asB, adB, Wo1, bo1, Wo2, bo2, Wo3, bo3, (float*)d_out, N);
    // layer 1: read dots B, write dots A
    gat_fused_kernel<<<NB32, 512, 0, stream>>>(
        buf1, asB, adB, rowptr, col, Wg[1], bg[1], vfold + 1024, 1,
        buf0, asA, adA, Wo1, bo1, Wo2, bo2, Wo3, bo3, (float*)d_out, N);
    // layer 2: read dots A, fused output MLP -> d_out
    gat_fused_kernel<<<NB32, 512, 0, stream>>>(
        buf0, asA, adA, rowptr, col, Wg[2], bg[2], vfold, 0,
        buf1, asB, adB, Wo1, bo1, Wo2, bo2, Wo3, bo3, (float*)d_out, N);
}

// Round 15
// 279.577 us; speedup vs baseline: 1.1693x; 1.1073x over previous
//
#include <hip/hip_runtime.h>
#include <cstdint>
#include <cstddef>

#define NEG_SLOPE 0.2f

__device__ __forceinline__ float elu_f(float x) {
    return x > 0.f ? x : expm1f(x);
}

// ---------------------------------------------------------------------------
// P0: zero cnt + ready, detect edge-index layout, compute folded attention
// vectors for all 3 layers. Blocks 0..78 zero; blocks 79..84 fold.
// vfold[l][k*8+j] = sum_cc W_l[k, h*64+cc]*att[h,cc] (j<4 src, j>=4 dst, h=j&3)
// ---------------------------------------------------------------------------
__global__ __launch_bounds__(256) void prep_kernel(
    const int* __restrict__ ei,
    const float* __restrict__ W0, const float* __restrict__ as0, const float* __restrict__ ad0,
    const float* __restrict__ W1, const float* __restrict__ as1, const float* __restrict__ ad1,
    const float* __restrict__ W2, const float* __restrict__ as2, const float* __restrict__ ad2,
    int* __restrict__ cnt, int* __restrict__ ready, int* __restrict__ flag,
    float* __restrict__ vfold, int n) {
    const int b = blockIdx.x, t = threadIdx.x;
    if (b < 79) {
        const int i = b * 256 + t;
        if (i < n) cnt[i] = 0;
        if (b == 0) {
            if (t < 128) ready[t] = 0;
            if (t == 0) {
                int acc = 0;
#pragma unroll
                for (int k = 0; k < 8; ++k) acc |= ei[2 * k + 1];
                flag[0] = (acc == 0) ? 1 : 0;
            }
        }
        return;
    }
    const int e = (b - 79) * 256 + t;
    if (e >= 1536) return;
    const int l = e >> 9, rem = e & 511;
    const int k = rem >> 3, j = rem & 7, h = j & 3;
    const float* W   = (l == 0) ? W0  : (l == 1) ? W1  : W2;
    const float* as_ = (l == 0) ? as0 : (l == 1) ? as1 : as2;
    const float* ad_ = (l == 0) ? ad0 : (l == 1) ? ad1 : ad2;
    const float* av = (j < 4) ? as_ : ad_;
    const float* wr = W + k * 256 + h * 64;
    const float* ar = av + h * 64;
    float s = 0.f;
#pragma unroll 8
    for (int cc = 0; cc < 64; ++cc) s += wr[cc] * ar[cc];
    vfold[l * 512 + k * 8 + j] = s;
}

__global__ void count_kernel(const int* __restrict__ ei, const int* __restrict__ flag,
                             int E, int Etot, int* __restrict__ cnt) {
    int e = blockIdx.x * blockDim.x + threadIdx.x;
    if (e >= Etot) return;
    int d;
    if (e < E) d = flag[0] ? ei[2 * (size_t)(E + e)] : ei[E + e];
    else       d = e - E;  // self loop
    atomicAdd(&cnt[d], 1);
}

// ---------------------------------------------------------------------------
// One-pass scan with parallel lookback (79 co-resident blocks).
// ---------------------------------------------------------------------------
#define SCAN_B 256
__global__ __launch_bounds__(256) void scan_onepass_kernel(
    const int* __restrict__ cnt, int* __restrict__ ready,
    int* __restrict__ rowptr, int* __restrict__ cursor, int n) {
    __shared__ int sd[SCAN_B];
    __shared__ int sred[128];
    __shared__ int s_pref;
    const int b = blockIdx.x, t = threadIdx.x;
    const int g = b * SCAN_B + t;
    const int v = (g < n) ? cnt[g] : 0;
    sd[t] = v;
    __syncthreads();
    for (int off = 1; off < SCAN_B; off <<= 1) {
        int add = (t >= off) ? sd[t - off] : 0;
        __syncthreads();
        sd[t] += add;
        __syncthreads();
    }
    if (t == SCAN_B - 1) atomicExch(&ready[b], sd[SCAN_B - 1] + 1);
    if (t < 128) {
        int pv = 0;
        if (t < b) {
            do { pv = atomicAdd(&ready[t], 0); __builtin_amdgcn_s_sleep(1); } while (pv == 0);
            pv -= 1;
        }
        sred[t] = pv;
    }
    __syncthreads();
    if (t == 0) {
        int s = 0;
#pragma unroll 8
        for (int i = 0; i < 128; ++i) s += sred[i];
        s_pref = s;
    }
    __syncthreads();
    const int pre = s_pref;
    if (g < n) {
        const int e = pre + sd[t];
        rowptr[g + 1] = e;
        cursor[g] = e - v;
        if (g == 0) rowptr[0] = 0;
    }
}

// ---------------------------------------------------------------------------
// fill (CSR scatter) + encoder merged into one dispatch: blocks [0,FB) do the
// CSR fill, blocks [FB, FB+ceil(N/64)) run the encoder.
// ---------------------------------------------------------------------------
#define H1STR 68
__global__ __launch_bounds__(256) void fillenc_kernel(
    const int* __restrict__ ei, const int* __restrict__ flag,
    int E, int Etot, int* __restrict__ cursor, int* __restrict__ col, int FB,
    const float* __restrict__ x,
    const float* __restrict__ W1, const float* __restrict__ b1,
    const float* __restrict__ W2, const float* __restrict__ b2,
    const float* __restrict__ vfold0,
    float* __restrict__ h0, float* __restrict__ asrc, float* __restrict__ adst,
    int n_nodes) {
    if (blockIdx.x < FB) {
        const int e = blockIdx.x * 256 + threadIdx.x;
        if (e >= Etot) return;
        int s, d;
        if (e < E) {
            if (flag[0]) { s = ei[2 * (size_t)e]; d = ei[2 * (size_t)(E + e)]; }
            else         { s = ei[e];             d = ei[E + e]; }
        } else {
            s = d = e - E;
        }
        int pos = atomicAdd(&cursor[d], 1);
        col[pos] = s;
        return;
    }
    __shared__ float W1s[256];
    __shared__ float b1s[32];
    __shared__ float W2s[2048];
    __shared__ float b2s[64];
    __shared__ float vsd[512];
    __shared__ float xS[512];            // 64 nodes x 8
    __shared__ float h1T[32 * H1STR];    // [k][node]
    const int t = threadIdx.x;
    const int n0 = (blockIdx.x - FB) * 64;
    const int rem = n_nodes - n0;

    *(float4*)(W2s + t * 4) = *(const float4*)(W2 + t * 4);
    *(float4*)(W2s + 1024 + t * 4) = *(const float4*)(W2 + 1024 + t * 4);
    if (t < 64)  *(float4*)(W1s + t * 4) = *(const float4*)(W1 + t * 4);
    if (t < 8)   *(float4*)(b1s + t * 4) = *(const float4*)(b1 + t * 4);
    if (t < 16)  *(float4*)(b2s + t * 4) = *(const float4*)(b2 + t * 4);
    if (t < 128) *(float4*)(vsd + t * 4) = *(const float4*)(vfold0 + t * 4);
    if (t < 128) {
        const int fidx = t * 4;
        float4 v = make_float4(0.f, 0.f, 0.f, 0.f);
        if (fidx < rem * 8) v = *(const float4*)(x + (size_t)n0 * 8 + fidx);
        *(float4*)(xS + fidx) = v;
    }
    __syncthreads();

    {
        const int nl = t >> 2;
        const int j0 = (t & 3) * 8;
        const float4 xa = *(const float4*)(xS + nl * 8);
        const float4 xb = *(const float4*)(xS + nl * 8 + 4);
        const float xk[8] = {xa.x, xa.y, xa.z, xa.w, xb.x, xb.y, xb.z, xb.w};
        float a[8];
#pragma unroll
        for (int u = 0; u < 8; ++u) a[u] = b1s[j0 + u];
#pragma unroll
        for (int k = 0; k < 8; ++k) {
            const float4 w0 = *(const float4*)(W1s + k * 32 + j0);
            const float4 w1 = *(const float4*)(W1s + k * 32 + j0 + 4);
            a[0] += xk[k] * w0.x; a[1] += xk[k] * w0.y;
            a[2] += xk[k] * w0.z; a[3] += xk[k] * w0.w;
            a[4] += xk[k] * w1.x; a[5] += xk[k] * w1.y;
            a[6] += xk[k] * w1.z; a[7] += xk[k] * w1.w;
        }
#pragma unroll
        for (int u = 0; u < 8; ++u) h1T[(j0 + u) * H1STR + nl] = elu_f(a[u]);
    }
    __syncthreads();

    const int cg = t & 15;
    const int nq = t >> 4;
    const int c0 = cg * 4;
    float acc[4][4];
#pragma unroll
    for (int i = 0; i < 4; ++i)
#pragma unroll
        for (int c = 0; c < 4; ++c) acc[i][c] = b2s[c0 + c];
#pragma unroll 8
    for (int k = 0; k < 32; ++k) {
        const float4 hv = *(const float4*)(h1T + k * H1STR + nq * 4);
        const float4 wv = *(const float4*)(W2s + k * 64 + c0);
        const float hvv[4] = {hv.x, hv.y, hv.z, hv.w};
#pragma unroll
        for (int i = 0; i < 4; ++i) {
            acc[i][0] += hvv[i] * wv.x; acc[i][1] += hvv[i] * wv.y;
            acc[i][2] += hvv[i] * wv.z; acc[i][3] += hvv[i] * wv.w;
        }
    }
    float o[4][4];
#pragma unroll
    for (int i = 0; i < 4; ++i)
#pragma unroll
        for (int c = 0; c < 4; ++c) o[i][c] = elu_f(acc[i][c]);

#pragma unroll
    for (int i = 0; i < 4; ++i) {
        const int n = n0 + nq * 4 + i;
        if (n < n_nodes)
            *(float4*)(h0 + (size_t)n * 64 + c0) =
                make_float4(o[i][0], o[i][1], o[i][2], o[i][3]);
    }
    float ad[4][8];
#pragma unroll
    for (int i = 0; i < 4; ++i)
#pragma unroll
        for (int jj = 0; jj < 8; ++jj) ad[i][jj] = 0.f;
#pragma unroll
    for (int c = 0; c < 4; ++c) {
        const float4 v0 = *(const float4*)(vsd + (c0 + c) * 8);
        const float4 v1 = *(const float4*)(vsd + (c0 + c) * 8 + 4);
#pragma unroll
        for (int i = 0; i < 4; ++i) {
            ad[i][0] += o[i][c] * v0.x; ad[i][1] += o[i][c] * v0.y;
            ad[i][2] += o[i][c] * v0.z; ad[i][3] += o[i][c] * v0.w;
            ad[i][4] += o[i][c] * v1.x; ad[i][5] += o[i][c] * v1.y;
            ad[i][6] += o[i][c] * v1.z; ad[i][7] += o[i][c] * v1.w;
        }
    }
#pragma unroll
    for (int off = 1; off < 16; off <<= 1) {
#pragma unroll
        for (int i = 0; i < 4; ++i)
#pragma unroll
            for (int jj = 0; jj < 8; ++jj)
                ad[i][jj] += __shfl_xor(ad[i][jj], off);
    }
    if (cg == 0) {
#pragma unroll
        for (int i = 0; i < 4; ++i) {
            const int n = n0 + nq * 4 + i;
            if (n < n_nodes) {
#pragma unroll
                for (int h = 0; h < 4; ++h) {
                    asrc[n * 4 + h] = ad[i][h];
                    adst[n * 4 + h] = ad[i][4 + h];
                }
            }
        }
    }
}

// ---------------------------------------------------------------------------
// Fused GAT layer (R2 exact form, session-best: 48.7 us/layer, 281.8 total).
// 32 nodes/block, 625 blocks, 512 threads, 1 node per 16-lane agg group,
// 4 blocks/CU. GEMM on t<256: 2 nodes x 4 cols x 4-k, b128 both operands.
// ---------------------------------------------------------------------------
#define GSTR 132
__global__ __launch_bounds__(512, 8) void gat_fused_kernel(
    const float* __restrict__ bin, const float* __restrict__ asrc,
    const float* __restrict__ adst, const int* __restrict__ rowptr,
    const int* __restrict__ col,
    const float* __restrict__ W, const float* __restrict__ bias,
    const float* __restrict__ vfold_next, int has_next,
    float* __restrict__ out,
    float* __restrict__ nasrc, float* __restrict__ nadst,
    const float* __restrict__ Wm1, const float* __restrict__ bm1,
    const float* __restrict__ Wm2, const float* __restrict__ bm2,
    const float* __restrict__ Wm3, const float* __restrict__ bm3,
    float* __restrict__ mlp_out, int n_nodes) {
    __shared__ float gS[32 * GSTR];   // 16,896 B
    __shared__ float Wp[4096];        // 16,384 B
    __shared__ float vN[512];         //  2,048 B
    const int t = threadIdx.x;
    const int n0 = blockIdx.x * 32;
    const int grp = t >> 4;           // 0..31 : ONE node per group (agg)
    const int q = t & 15;             // lane in group
    const int c0 = q * 4;

    if (has_next && t < 128) *(float4*)(vN + t * 4) = *(const float4*)(vfold_next + t * 4);

    // ============ phase 1: aggregation (1 node per 16-lane group) ============
    float keep[8];                    // normalized heads {2,3}
    {
        const int n = n0 + grp;
        float acc[4][4];
#pragma unroll
        for (int h = 0; h < 4; ++h)
#pragma unroll
            for (int z = 0; z < 4; ++z) acc[h][z] = 0.f;
        if (n < n_nodes) {
            float4 den4 = make_float4(0.f, 0.f, 0.f, 0.f);
            const float4 ad4 = *(const float4*)(adst + (size_t)n * 4);
            const int start = rowptr[n], end = rowptr[n + 1];
            for (int base = start; base < end; base += 16) {
                const int cnt = min(16, end - base);
                int c = 0;
                float4 w4 = make_float4(0.f, 0.f, 0.f, 0.f);
                if (base + q < end) {
                    c = col[base + q];
                    const float4 av = *(const float4*)(asrc + (size_t)c * 4);
                    float l0 = av.x + ad4.x; l0 = l0 > 0.f ? l0 : NEG_SLOPE * l0;
                    float l1 = av.y + ad4.y; l1 = l1 > 0.f ? l1 : NEG_SLOPE * l1;
                    float l2 = av.z + ad4.z; l2 = l2 > 0.f ? l2 : NEG_SLOPE * l2;
                    float l3 = av.w + ad4.w; l3 = l3 > 0.f ? l3 : NEG_SLOPE * l3;
                    w4.x = __expf(fminf(l0, 60.f));
                    w4.y = __expf(fminf(l1, 60.f));
                    w4.z = __expf(fminf(l2, 60.f));
                    w4.w = __expf(fminf(l3, 60.f));
                    den4.x += w4.x; den4.y += w4.y; den4.z += w4.z; den4.w += w4.w;
                }
                int j = 0;
                for (; j + 4 <= cnt; j += 4) {
#pragma unroll
                    for (int u = 0; u < 4; ++u) {
                        const int s = __shfl(c, j + u, 16);
                        const float4 hv = *(const float4*)(bin + (size_t)s * 64 + q * 4);
                        const float wx = __shfl(w4.x, j + u, 16);
                        const float wy = __shfl(w4.y, j + u, 16);
                        const float wz = __shfl(w4.z, j + u, 16);
                        const float ww = __shfl(w4.w, j + u, 16);
                        acc[0][0] += wx * hv.x; acc[0][1] += wx * hv.y;
                        acc[0][2] += wx * hv.z; acc[0][3] += wx * hv.w;
                        acc[1][0] += wy * hv.x; acc[1][1] += wy * hv.y;
                        acc[1][2] += wy * hv.z; acc[1][3] += wy * hv.w;
                        acc[2][0] += wz * hv.x; acc[2][1] += wz * hv.y;
                        acc[2][2] += wz * hv.z; acc[2][3] += wz * hv.w;
                        acc[3][0] += ww * hv.x; acc[3][1] += ww * hv.y;
                        acc[3][2] += ww * hv.z; acc[3][3] += ww * hv.w;
                    }
                }
                for (; j < cnt; ++j) {
                    const int s = __shfl(c, j, 16);
                    const float4 hv = *(const float4*)(bin + (size_t)s * 64 + q * 4);
                    const float wx = __shfl(w4.x, j, 16);
                    const float wy = __shfl(w4.y, j, 16);
                    const float wz = __shfl(w4.z, j, 16);
                    const float ww = __shfl(w4.w, j, 16);
                    acc[0][0] += wx * hv.x; acc[0][1] += wx * hv.y;
                    acc[0][2] += wx * hv.z; acc[0][3] += wx * hv.w;
                    acc[1][0] += wy * hv.x; acc[1][1] += wy * hv.y;
                    acc[1][2] += wy * hv.z; acc[1][3] += wy * hv.w;
                    acc[2][0] += wz * hv.x; acc[2][1] += wz * hv.y;
                    acc[2][2] += wz * hv.z; acc[2][3] += wz * hv.w;
                    acc[3][0] += ww * hv.x; acc[3][1] += ww * hv.y;
                    acc[3][2] += ww * hv.z; acc[3][3] += ww * hv.w;
                }
            }
#pragma unroll
            for (int off = 1; off < 16; off <<= 1) {
                den4.x += __shfl_xor(den4.x, off, 16);
                den4.y += __shfl_xor(den4.y, off, 16);
                den4.z += __shfl_xor(den4.z, off, 16);
                den4.w += __shfl_xor(den4.w, off, 16);
            }
            const float i0 = 1.f / (den4.x + 1e-16f);
            const float i1 = 1.f / (den4.y + 1e-16f);
            const float i2 = 1.f / (den4.z + 1e-16f);
            const float i3 = 1.f / (den4.w + 1e-16f);
            *(float4*)(gS + grp * GSTR + c0) =
                make_float4(acc[0][0] * i0, acc[0][1] * i0, acc[0][2] * i0, acc[0][3] * i0);
            *(float4*)(gS + grp * GSTR + 64 + c0) =
                make_float4(acc[1][0] * i1, acc[1][1] * i1, acc[1][2] * i1, acc[1][3] * i1);
            keep[0] = acc[2][0] * i2; keep[1] = acc[2][1] * i2;
            keep[2] = acc[2][2] * i2; keep[3] = acc[2][3] * i2;
            keep[4] = acc[3][0] * i3; keep[5] = acc[3][1] * i3;
            keep[6] = acc[3][2] * i3; keep[7] = acc[3][3] * i3;
        } else {
            const float4 z4 = make_float4(0.f, 0.f, 0.f, 0.f);
            *(float4*)(gS + grp * GSTR + c0) = z4;
            *(float4*)(gS + grp * GSTR + 64 + c0) = z4;
#pragma unroll
            for (int u = 0; u < 8; ++u) keep[u] = 0.f;
        }
    }

    // ============ phase 2: head-mean projection GEMM ============
    const int ng2 = t >> 4;           // valid when t<256
    float ga2[2][4];
#pragma unroll
    for (int i = 0; i < 2; ++i)
#pragma unroll
        for (int c = 0; c < 4; ++c) ga2[i][c] = 0.f;

#pragma unroll
    for (int half = 0; half < 2; ++half) {
        if (half == 1) {
            // last half-0 barrier passed: swap heads {2,3} into gS
            *(float4*)(gS + grp * GSTR + c0) =
                make_float4(keep[0], keep[1], keep[2], keep[3]);
            *(float4*)(gS + grp * GSTR + 64 + c0) =
                make_float4(keep[4], keep[5], keep[6], keep[7]);
        }
#pragma unroll
        for (int s = 0; s < 2; ++s) {
#pragma unroll
            for (int j = 0; j < 2; ++j) {
                const int f4 = j * 512 + t;
                const int kl = f4 >> 4;
                const int c = (f4 & 15) * 4;
                const int m = half * 128 + s * 64 + kl;
                const int h = m >> 6, kk = m & 63;
                *(float4*)(Wp + kl * 64 + c) = *(const float4*)(W + kk * 256 + h * 64 + c);
            }
            __syncthreads();
            if (t < 256) {
#pragma unroll 4
                for (int ks = 0; ks < 64; ks += 4) {
                    const float4 a0 = *(const float4*)(gS + (ng2 * 2 + 0) * GSTR + s * 64 + ks);
                    const float4 a1 = *(const float4*)(gS + (ng2 * 2 + 1) * GSTR + s * 64 + ks);
                    const float4 w0 = *(const float4*)(Wp + (ks + 0) * 64 + c0);
                    const float4 w1 = *(const float4*)(Wp + (ks + 1) * 64 + c0);
                    const float4 w2 = *(const float4*)(Wp + (ks + 2) * 64 + c0);
                    const float4 w3 = *(const float4*)(Wp + (ks + 3) * 64 + c0);
                    ga2[0][0] += a0.x * w0.x + a0.y * w1.x + a0.z * w2.x + a0.w * w3.x;
                    ga2[0][1] += a0.x * w0.y + a0.y * w1.y + a0.z * w2.y + a0.w * w3.y;
                    ga2[0][2] += a0.x * w0.z + a0.y * w1.z + a0.z * w2.z + a0.w * w3.z;
                    ga2[0][3] += a0.x * w0.w + a0.y * w1.w + a0.z * w2.w + a0.w * w3.w;
                    ga2[1][0] += a1.x * w0.x + a1.y * w1.x + a1.z * w2.x + a1.w * w3.x;
                    ga2[1][1] += a1.x * w0.y + a1.y * w1.y + a1.z * w2.y + a1.w * w3.y;
                    ga2[1][2] += a1.x * w0.z + a1.y * w1.z + a1.z * w2.z + a1.w * w3.z;
                    ga2[1][3] += a1.x * w0.w + a1.y * w1.w + a1.z * w2.w + a1.w * w3.w;
                }
            }
            __syncthreads();
        }
    }

    // ============ epilogue: bias + head-mean + residual (t<256) ============
    float o[2][4];
    if (t < 256) {
        const float4 bb = *(const float4*)(bias + c0);
#pragma unroll
        for (int i = 0; i < 2; ++i) {
            const int n = n0 + ng2 * 2 + i;
            if (n < n_nodes) {
                const float4 x4 = *(const float4*)(bin + (size_t)n * 64 + c0);
                o[i][0] = 0.25f * ga2[i][0] + bb.x + x4.x;
                o[i][1] = 0.25f * ga2[i][1] + bb.y + x4.y;
                o[i][2] = 0.25f * ga2[i][2] + bb.z + x4.z;
                o[i][3] = 0.25f * ga2[i][3] + bb.w + x4.w;
                if (has_next)
                    *(float4*)(out + (size_t)n * 64 + c0) =
                        make_float4(o[i][0], o[i][1], o[i][2], o[i][3]);
            } else {
                o[i][0] = o[i][1] = o[i][2] = o[i][3] = 0.f;
            }
        }
    } else {
#pragma unroll
        for (int i = 0; i < 2; ++i)
            o[i][0] = o[i][1] = o[i][2] = o[i][3] = 0.f;
    }

    if (has_next) {
        if (t < 256) {
            float pj[2][8];
#pragma unroll
            for (int i = 0; i < 2; ++i)
#pragma unroll
                for (int jj = 0; jj < 8; ++jj) pj[i][jj] = 0.f;
#pragma unroll
            for (int c = 0; c < 4; ++c) {
                const float4 v0 = *(const float4*)(vN + (c0 + c) * 8);
                const float4 v1 = *(const float4*)(vN + (c0 + c) * 8 + 4);
#pragma unroll
                for (int i = 0; i < 2; ++i) {
                    pj[i][0] += o[i][c] * v0.x; pj[i][1] += o[i][c] * v0.y;
                    pj[i][2] += o[i][c] * v0.z; pj[i][3] += o[i][c] * v0.w;
                    pj[i][4] += o[i][c] * v1.x; pj[i][5] += o[i][c] * v1.y;
                    pj[i][6] += o[i][c] * v1.z; pj[i][7] += o[i][c] * v1.w;
                }
            }
#pragma unroll
            for (int off = 1; off < 16; off <<= 1) {
#pragma unroll
                for (int i = 0; i < 2; ++i)
#pragma unroll
                    for (int jj = 0; jj < 8; ++jj)
                        pj[i][jj] += __shfl_xor(pj[i][jj], off);
            }
            if (q == 0) {
#pragma unroll
                for (int i = 0; i < 2; ++i) {
                    const int n = n0 + ng2 * 2 + i;
                    if (n < n_nodes) {
#pragma unroll
                        for (int h = 0; h < 4; ++h) {
                            nasrc[n * 4 + h] = pj[i][h];
                            nadst[n * 4 + h] = pj[i][4 + h];
                        }
                    }
                }
            }
        }
        return;
    }

    // ============ fused output MLP 64->64->32->8 (last layer, 32 nodes) =====
    if (t < 256) {
#pragma unroll
        for (int i = 0; i < 2; ++i)
            *(float4*)(gS + (ng2 * 2 + i) * GSTR + c0) =
                make_float4(o[i][0], o[i][1], o[i][2], o[i][3]);
    }
#pragma unroll
    for (int j = 0; j < 2; ++j)
        *(float4*)(Wp + (j * 512 + t) * 4) = *(const float4*)(Wm1 + (j * 512 + t) * 4);
    if (t < 64) vN[t] = bm1[t];
    else if (t < 96) vN[t] = bm2[t - 64];
    else if (t < 104) vN[t] = bm3[t - 96];
    if (t < 256) vN[104 + t] = Wm3[t];
    __syncthreads();
    // MLP1: 32 nodes x 64 cols, thread (t<256) = 1 node x 8 cols
    if (t < 256) {
        const int ng = t >> 3;            // 0..31
        const int cm0 = (t & 7) * 8;
        float a1[8];
#pragma unroll
        for (int u = 0; u < 8; ++u) a1[u] = vN[cm0 + u];
#pragma unroll 4
        for (int k = 0; k < 64; ++k) {
            const float hv = gS[ng * GSTR + k];
            const float4 w0 = *(const float4*)(Wp + k * 64 + cm0);
            const float4 w1 = *(const float4*)(Wp + k * 64 + cm0 + 4);
            a1[0] += hv * w0.x; a1[1] += hv * w0.y;
            a1[2] += hv * w0.z; a1[3] += hv * w0.w;
            a1[4] += hv * w1.x; a1[5] += hv * w1.y;
            a1[6] += hv * w1.z; a1[7] += hv * w1.w;
        }
        *(float4*)(gS + ng * GSTR + 64 + cm0) =
            make_float4(elu_f(a1[0]), elu_f(a1[1]), elu_f(a1[2]), elu_f(a1[3]));
        *(float4*)(gS + ng * GSTR + 64 + cm0 + 4) =
            make_float4(elu_f(a1[4]), elu_f(a1[5]), elu_f(a1[6]), elu_f(a1[7]));
    }
    __syncthreads();
    *(float4*)(Wp + t * 4) = *(const float4*)(Wm2 + t * 4);
    __syncthreads();
    // MLP2: 32 nodes x 32 cols, thread (t<256) = 1 node x 4 cols
    if (t < 256) {
        const int nn = t >> 3;            // 0..31
        const int cc0 = (t & 7) * 4;
        float a2[4];
#pragma unroll
        for (int u = 0; u < 4; ++u) a2[u] = vN[64 + cc0 + u];
#pragma unroll 4
        for (int j = 0; j < 64; ++j) {
            const float ov = gS[nn * GSTR + 64 + j];
            const float4 w = *(const float4*)(Wp + j * 32 + cc0);
            a2[0] += ov * w.x; a2[1] += ov * w.y;
            a2[2] += ov * w.z; a2[3] += ov * w.w;
        }
        __syncthreads();
        *(float4*)(gS + nn * GSTR + cc0) =
            make_float4(elu_f(a2[0]), elu_f(a2[1]), elu_f(a2[2]), elu_f(a2[3]));
    } else {
        __syncthreads();
    }
    __syncthreads();
    // MLP3: 32 nodes x 8 cols, thread (t<256) = 1 output
    if (t < 256) {
        const int nl = t >> 3;
        const int c3 = t & 7;
        const int n = n0 + nl;
        if (n < n_nodes) {
            float a3 = vN[96 + c3];
#pragma unroll 4
            for (int j = 0; j < 32; ++j)
                a3 += gS[nl * GSTR + j] * vN[104 + j * 8 + c3];
            mlp_out[(size_t)n * 8 + c3] = a3;
        }
    }
}

// ---------------------------------------------------------------------------
extern "C" void kernel_launch(void* const* d_in, const int* in_sizes, int n_in,
                              void* d_out, int out_size, void* d_ws, size_t ws_size,
                              hipStream_t stream) {
    const float* x     = (const float*)d_in[0];
    const int*   ei    = (const int*)d_in[1];
    const float* Wenc1 = (const float*)d_in[2];
    const float* benc1 = (const float*)d_in[3];
    const float* Wenc2 = (const float*)d_in[4];
    const float* benc2 = (const float*)d_in[5];
    const float* Wg[3]  = {(const float*)d_in[6],  (const float*)d_in[10], (const float*)d_in[14]};
    const float* as_[3] = {(const float*)d_in[7],  (const float*)d_in[11], (const float*)d_in[15]};
    const float* ad_[3] = {(const float*)d_in[8],  (const float*)d_in[12], (const float*)d_in[16]};
    const float* bg[3]  = {(const float*)d_in[9],  (const float*)d_in[13], (const float*)d_in[17]};
    const float* Wo1 = (const float*)d_in[18];
    const float* bo1 = (const float*)d_in[19];
    const float* Wo2 = (const float*)d_in[20];
    const float* bo2 = (const float*)d_in[21];
    const float* Wo3 = (const float*)d_in[22];
    const float* bo3 = (const float*)d_in[23];

    const int N = in_sizes[0] / 8;
    const int E = in_sizes[1] / 2;
    const int Etot = E + N;
    const int nblk = (N + SCAN_B - 1) / SCAN_B;  // 79
    const int FB = (Etot + 255) / 256;
    const int NB64 = (N + 63) / 64;
    const int NB32 = (N + 31) / 32;

    float* buf0  = (float*)d_ws;                  // N*64
    float* buf1  = buf0 + (size_t)N * 64;         // N*64
    float* asA   = buf1 + (size_t)N * 64;         // N*4
    float* adA   = asA + (size_t)N * 4;           // N*4
    float* asB   = adA + (size_t)N * 4;           // N*4
    float* adB   = asB + (size_t)N * 4;           // N*4
    float* vfold = adB + (size_t)N * 4;           // 3*512
    int* rowptr = (int*)(vfold + 3 * 512);        // N+1 (+pad)
    int* cursor = rowptr + (N + 2);               // N
    int* cnt    = cursor + N;                     // N
    int* ready  = cnt + N;                        // 128
    int* flag   = ready + 128;                    // 1 (+pad)
    int* col    = flag + 2;                       // Etot

    prep_kernel<<<nblk + 6, 256, 0, stream>>>(ei,
        Wg[0], as_[0], ad_[0], Wg[1], as_[1], ad_[1], Wg[2], as_[2], ad_[2],
        cnt, ready, flag, vfold, N);
    count_kernel<<<(Etot + 255) / 256, 256, 0, stream>>>(ei, flag, E, Etot, cnt);
    scan_onepass_kernel<<<nblk, SCAN_B, 0, stream>>>(cnt, ready, rowptr, cursor, N);
    fillenc_kernel<<<FB + NB64, 256, 0, stream>>>(ei, flag, E, Etot, cursor, col, FB,
                                                  x, Wenc1, benc1, Wenc2, benc2,
                                                  vfold, buf0, asA, adA, N);

    // layer 0: read dots A, write dots B
    gat_fused_kernel<<<NB32, 512, 0, stream>>>(
        buf0, asA, adA, rowptr, col, Wg[0], bg[0], vfold + 512, 1,
        buf1, asB, adB, Wo1, bo1, Wo2, bo2, Wo3, bo3, (float*)d_out, N);
    // layer 1: read dots B, write dots A
    gat_fused_kernel<<<NB32, 512, 0, stream>>>(
        buf1, asB, adB, rowptr, col, Wg[1], bg[1], vfold + 1024, 1,
        buf0, asA, adA, Wo1, bo1, Wo2, bo2, Wo3, bo3, (float*)d_out, N);
    // layer 2: read dots A, fused output MLP -> d_out
    gat_fused_kernel<<<NB32, 512, 0, stream>>>(
        buf0, asA, adA, rowptr, col, Wg[2], bg[2], vfold, 0,
        buf1, asB, adB, Wo1, bo1, Wo2, bo2, Wo3, bo3, (float*)d_out, N);
}